// Round 2
// 309.416 us; speedup vs baseline: 1.3489x; 1.3489x over previous
//
#include <hip/hip_runtime.h>

typedef unsigned int u32;
typedef unsigned short u16;
typedef _Float16 f16;
typedef __attribute__((ext_vector_type(8))) _Float16 f16x8;
typedef __attribute__((ext_vector_type(4))) float f32x4;

#define MARGIN 1e-2f

__device__ __forceinline__ u16 f16b(float f) {
    return __builtin_bit_cast(u16, (f16)f);
}
__device__ __forceinline__ f32x4 MF(f16x8 a, f16x8 b, f32x4 c) {
    return __builtin_amdgcn_mfma_f32_16x16x32_f16(a, b, c, 0, 0, 0);
}
__device__ __forceinline__ uint4 pack8(const u16 v[8]) {
    uint4 pk;
    pk.x = (u32)v[0] | ((u32)v[1] << 16);
    pk.y = (u32)v[2] | ((u32)v[3] << 16);
    pk.z = (u32)v[4] | ((u32)v[5] << 16);
    pk.w = (u32)v[6] | ((u32)v[7] << 16);
    return pk;
}

// ---------------------------------------------------------------------------
// conv: weights -> f16 MFMA-fragment-linear layouts + fp32 transposes for fix.
// frag(nf,kk) of a [K x N] matrix: lane l (ln=l&15, quad=l>>4) holds 8 f16
//   = W[kk*32+quad*8+j][nf*16+ln], stored at (nf*8+kk)*512 + l*8 (u16 units).
// blocks 0..31: Wt1 (N=512 -> nf 0..31, K=256 -> kk 0..7)
// blocks 32..111: Wp1 per p (N=128 -> nf 0..7, kk 0..7)
// block 112: wt2f (K=512, C pad 16), wp2f (K=128), wt2t/wp2t fp32, gcnt=0
// ---------------------------------------------------------------------------
__global__ __launch_bounds__(256) void conv_kernel(
    const float* __restrict__ Wt1, const float* __restrict__ Wp1,
    const float* __restrict__ Wt2, const float* __restrict__ Wp2,
    u16* __restrict__ wt1f, u16* __restrict__ wp1f,
    u16* __restrict__ wt2f, u16* __restrict__ wp2f,
    float* __restrict__ wt2t, float* __restrict__ wp2t, u32* __restrict__ gcnt)
{
    __shared__ float tile[64][68];
    const int t = threadIdx.x;
    const int b = blockIdx.x;

    if (b == 112) {
        if (t == 0) gcnt[0] = 0;
        for (int i = t; i < 5120; i += 256) {
            int n = i / 10, c = i % 10;
            wt2t[c * 512 + n] = Wt2[i];
        }
        for (int i = t; i < 12800; i += 256) {
            int p = i / 1280, r = i % 1280, n = r / 10, c = r % 10;
            wp2t[p * 1280 + c * 128 + n] = Wp2[i];
        }
        // wt2f: 16 kk-frags of Wt2 [512 x 10->16]
        for (int cc = t; cc < 1024; cc += 256) {
            int kk = cc >> 6, l = cc & 63, ln = l & 15, quad = l >> 4;
            u16 v[8];
            #pragma unroll
            for (int j = 0; j < 8; ++j) {
                int k = kk * 32 + quad * 8 + j;
                v[j] = f16b(ln < 10 ? Wt2[k * 10 + ln] : 0.f);
            }
            uint4 pk = pack8(v);
            *(uint4*)(wt2f + kk * 512 + l * 8) = pk;
        }
        // wp2f: per p, 4 kk-frags of Wp2[p] [128 x 10->16]
        for (int cc = t; cc < 2560; cc += 256) {
            int p = cc >> 8, rem = cc & 255, kk = rem >> 6, l = rem & 63;
            int ln = l & 15, quad = (l >> 4) & 3;
            u16 v[8];
            #pragma unroll
            for (int j = 0; j < 8; ++j) {
                int k = kk * 32 + quad * 8 + j;
                v[j] = f16b(ln < 10 ? Wp2[p * 1280 + k * 10 + ln] : 0.f);
            }
            uint4 pk = pack8(v);
            *(uint4*)(wp2f + p * 2048 + kk * 512 + l * 8) = pk;
        }
        return;
    }

    const float* src; int src_ld;
    u16* dst; int nf0, kk0;
    if (b < 32) {
        int kt = b & 3, nt = b >> 2;
        src = Wt1 + (size_t)(kt * 64) * 512 + nt * 64; src_ld = 512;
        dst = wt1f; nf0 = nt * 4; kk0 = kt * 2;
    } else {
        int j = b - 32, p = j >> 3, r = j & 7;
        int kt = r & 3, nt = r >> 2;
        src = Wp1 + (size_t)p * 32768 + (size_t)(kt * 64) * 128 + nt * 64; src_ld = 128;
        dst = wp1f + p * 32768; nf0 = nt * 4; kk0 = kt * 2;
    }
    {
        const int kr = t >> 2, c0 = (t & 3) * 16;
        #pragma unroll
        for (int u = 0; u < 4; ++u) {
            float4 v = *(const float4*)(src + (size_t)kr * src_ld + c0 + u * 4);
            tile[kr][c0 + u*4 + 0] = v.x;
            tile[kr][c0 + u*4 + 1] = v.y;
            tile[kr][c0 + u*4 + 2] = v.z;
            tile[kr][c0 + u*4 + 3] = v.w;
        }
    }
    __syncthreads();
    #pragma unroll
    for (int s = 0; s < 2; ++s) {
        int cc = t + 256 * s;              // 512 chunks per 64x64 tile
        int l = cc & 63, fp = cc >> 6, nfl = fp >> 1, kkl = fp & 1;
        int ln = l & 15, quad = (l >> 4) & 3;
        int nloc = nfl * 16 + ln, kloc = kkl * 32 + quad * 8;
        u16 v[8];
        #pragma unroll
        for (int j = 0; j < 8; ++j) v[j] = f16b(tile[kloc + j][nloc]);
        uint4 pk = pack8(v);
        *(uint4*)(dst + (size_t)((nf0 + nfl) * 8 + (kk0 + kkl)) * 512 + l * 8) = pk;
    }
}

// ---------------------------------------------------------------------------
// netsum: per 64-row block: stage x->f16 LDS; layer1 f16 MFMA (n in 2 halves,
// h -> LDS); layer2 via MFMA; margin rows -> global list (fixed by fix_kernel);
// bitmap + gated patch nets fully in MFMA (per-wave h_p scratch in hbuf).
// ---------------------------------------------------------------------------
__global__ __launch_bounds__(512, 4) void netsum_kernel(
    const float* __restrict__ x, const float* __restrict__ bt1,
    const float* __restrict__ bt2,
    const float* __restrict__ bp1, const float* __restrict__ bp2,
    const int* __restrict__ rdd,
    const u16* __restrict__ wt1f, const u16* __restrict__ wp1f,
    const u16* __restrict__ wt2f, const u16* __restrict__ wp2f,
    float* __restrict__ out, u32* __restrict__ gcnt, u32* __restrict__ glist)
{
    __shared__ u16 xf[64][264];      // 33792 B  (x in f16, row stride 528B)
    __shared__ u16 hbuf[17408];      // 34816 B  h-half [64][264] / patch hp 8x2176
    __shared__ float lg[64][10];
    __shared__ float oacc[64][10];
    __shared__ u32 plist[10][64];
    __shared__ u32 pcnt[10];
    __shared__ int rdds[20];
    __shared__ u32 wq[40];
    __shared__ u32 nwork;
    // total ~76.5 KB -> 2 blocks/CU

    const int t = threadIdx.x;
    const int lane = t & 63;
    const int w = t >> 6;
    const int ln = lane & 15;
    const int quad = lane >> 4;
    const int row0 = blockIdx.x * 64;

    if (t < 10) pcnt[t] = 0;
    if (t < 20) rdds[t] = rdd[t];
    if (t == 0) nwork = 0;
    for (int i = t; i < 640; i += 512) ((float*)oacc)[i] = 0.f;

    // ---- stage x -> f16 LDS (coalesced) ----
    #pragma unroll
    for (int i = 0; i < 8; ++i) {
        int f = t + 512 * i;           // float4 index 0..4095
        int r = f >> 6, c4 = f & 63;
        float4 v = *(const float4*)(x + (size_t)(row0 + r) * 256 + c4 * 4);
        u16 q0 = f16b(v.x), q1 = f16b(v.y), q2 = f16b(v.z), q3 = f16b(v.w);
        uint2 pw = { (u32)q0 | ((u32)q1 << 16), (u32)q2 | ((u32)q3 << 16) };
        *(uint2*)&xf[r][c4 * 4] = pw;
    }
    __syncthreads();

    // ---- layer 1 (f16 MFMA, coalesced frag-linear B) + layer 2 (MFMA) ----
    f32x4 acc2 = (f32x4){0.f, 0.f, 0.f, 0.f};   // layer-2 accum (waves 0..3)
    for (int hl = 0; hl < 2; ++hl) {
        f32x4 acc[4][2];
        #pragma unroll
        for (int m = 0; m < 4; ++m) {
            acc[m][0] = (f32x4){0.f,0.f,0.f,0.f};
            acc[m][1] = (f32x4){0.f,0.f,0.f,0.f};
        }
        // wave w owns n = hl*256 + w*32 + i2*16 + ln
        const u16* bb = wt1f + (size_t)(hl * 16 + w * 2) * 4096 + lane * 8;
        for (int kk = 0; kk < 8; ++kk) {
            f16x8 b0 = *(const f16x8*)(bb + kk * 512);
            f16x8 b1 = *(const f16x8*)(bb + 4096 + kk * 512);
            #pragma unroll
            for (int m = 0; m < 4; ++m) {
                f16x8 a = *(const f16x8*)(&xf[m * 16 + ln][kk * 32 + quad * 8]);
                acc[m][0] = MF(a, b0, acc[m][0]);
                acc[m][1] = MF(a, b1, acc[m][1]);
            }
        }
        // bias + relu + f16 -> hbuf [64][264]
        #pragma unroll
        for (int m = 0; m < 4; ++m)
            #pragma unroll
            for (int i2 = 0; i2 < 2; ++i2) {
                int nloc = w * 32 + i2 * 16 + ln;
                float bias = bt1[hl * 256 + nloc];
                #pragma unroll
                for (int r = 0; r < 4; ++r) {
                    float hv = acc[m][i2][r] + bias; hv = hv > 0.f ? hv : 0.f;
                    hbuf[(m * 16 + quad * 4 + r) * 264 + nloc] = f16b(hv);
                }
            }
        __syncthreads();
        // layer 2: waves 0..3, wave w = m-frag w, K=256 per half
        if (w < 4) {
            #pragma unroll
            for (int kk = 0; kk < 8; ++kk) {
                f16x8 ha = *(const f16x8*)(&hbuf[(w * 16 + ln) * 264 + kk * 32 + quad * 8]);
                f16x8 wb = *(const f16x8*)(wt2f + (hl * 8 + kk) * 512 + lane * 8);
                acc2 = MF(ha, wb, acc2);
            }
        }
        __syncthreads();   // before next half overwrites hbuf
    }
    if (w < 4 && ln < 10) {
        #pragma unroll
        for (int r = 0; r < 4; ++r)
            lg[w * 16 + quad * 4 + r][ln] = acc2[r] + bt2[ln];
    }
    __syncthreads();

    // ---- margin flag (-> global list) + bitmap + per-patch row lists ----
    if (t < 64) {
        float l[10];
        #pragma unroll
        for (int c = 0; c < 10; ++c) l[c] = lg[t][c];
        float b0 = -1e30f; int i0 = 0;
        #pragma unroll
        for (int c = 0; c < 10; ++c) if (l[c] > b0) { b0 = l[c]; i0 = c; }
        float b1 = -1e30f; int i1 = 0;
        #pragma unroll
        for (int c = 0; c < 10; ++c) { if (c == i0) continue; if (l[c] > b1) { b1 = l[c]; i1 = c; } }
        float b2v = -1e30f;
        #pragma unroll
        for (int c = 0; c < 10; ++c) { if (c == i0 || c == i1) continue; if (l[c] > b2v) b2v = l[c]; }
        if (b0 - b1 < MARGIN || b1 - b2v < MARGIN) {
            u32 idx = atomicAdd(gcnt, 1u);
            glist[idx] = (u32)(row0 + t);
        }
        u32 exact = 0, fb = 0;
        #pragma unroll
        for (int p = 0; p < 10; ++p) {
            int a = rdds[2 * p], bq = rdds[2 * p + 1];
            if (i0 == a && i1 == bq) exact |= 1u << p;
            if (i0 == a)             fb    |= 1u << p;
        }
        u32 bits = exact ? exact : fb;
        while (bits) {
            int p = __ffs(bits) - 1;
            bits &= bits - 1;
            u32 idx = atomicAdd(&pcnt[p], 1u);
            plist[p][idx] = (u32)t;
        }
    }
    __syncthreads();
    if (t < 10) {
        int L = (int)pcnt[t];
        for (int base = 0; base < L; base += 16) {
            u32 e = atomicAdd(&nwork, 1u);
            wq[e] = ((u32)t << 8) | (u32)base;
        }
    }
    __syncthreads();

    // ---- gated patch nets: f16 MFMA layer1 + MFMA layer2 (per-wave hp) ----
    {
        const u32 nw = nwork;
        for (u32 ii = w; ii < nw; ii += 8) {
            const u32 item = wq[ii];
            const int p = (int)(item >> 8), mbase = (int)(item & 255);
            const int Lp = (int)pcnt[p];
            const int mi = mbase + ln;
            const int arow = (mi < Lp) ? (int)plist[p][mi] : (int)plist[p][0];
            const u16* xr = &xf[arow][0];
            const u16* wb = wp1f + (size_t)p * 32768 + lane * 8;
            f32x4 pacc[8];
            #pragma unroll
            for (int i2 = 0; i2 < 8; ++i2) pacc[i2] = (f32x4){0.f,0.f,0.f,0.f};
            for (int kk = 0; kk < 8; ++kk) {
                f16x8 a = *(const f16x8*)(xr + kk * 32 + quad * 8);
                #pragma unroll
                for (int i2 = 0; i2 < 8; ++i2) {
                    f16x8 bb2 = *(const f16x8*)(wb + (i2 * 8 + kk) * 512);
                    pacc[i2] = MF(a, bb2, pacc[i2]);
                }
            }
            // hp: [16][136] per-wave scratch (row stride 272B)
            u16* hp = &hbuf[w * 2176];
            #pragma unroll
            for (int i2 = 0; i2 < 8; ++i2) {
                float bias = bp1[p * 128 + i2 * 16 + ln];
                #pragma unroll
                for (int r = 0; r < 4; ++r) {
                    float hv = pacc[i2][r] + bias; hv = hv > 0.f ? hv : 0.f;
                    hp[(quad * 4 + r) * 136 + i2 * 16 + ln] = f16b(hv);
                }
            }
            f32x4 po = (f32x4){0.f,0.f,0.f,0.f};
            #pragma unroll
            for (int kk = 0; kk < 4; ++kk) {
                f16x8 ha = *(const f16x8*)(&hp[ln * 136 + kk * 32 + quad * 8]);
                f16x8 wb2 = *(const f16x8*)(wp2f + p * 2048 + kk * 512 + lane * 8);
                po = MF(ha, wb2, po);
            }
            if (ln < 10) {
                float b2 = bp2[p * 10 + ln];
                #pragma unroll
                for (int r = 0; r < 4; ++r) {
                    int mi2 = mbase + quad * 4 + r;
                    if (mi2 < Lp)
                        atomicAdd(&oacc[plist[p][mi2]][ln], po[r] + b2);
                }
            }
        }
    }
    __syncthreads();

    for (int i = t; i < 640; i += 512)
        out[(size_t)row0 * 10 + i] = ((float*)lg)[i] + ((float*)oacc)[i];
}

// ---------------------------------------------------------------------------
// fix: exact fp32 recompute for margin-flagged rows (target net + bitmap +
// patch nets + final out). 8 rows/block, coalesced column reads of fp32 weights.
// ---------------------------------------------------------------------------
__global__ __launch_bounds__(512) void fix_kernel(
    const float* __restrict__ x, const float* __restrict__ Wt1,
    const float* __restrict__ bt1, const float* __restrict__ bt2,
    const float* __restrict__ Wp1, const float* __restrict__ bp1,
    const float* __restrict__ bp2, const int* __restrict__ rdd,
    const float* __restrict__ wt2t, const float* __restrict__ wp2t,
    const u32* __restrict__ gcnt, const u32* __restrict__ glist,
    float* __restrict__ out)
{
    __shared__ float xs[8][256];
    __shared__ float lgx[8][10];
    __shared__ float oax[8][10];
    __shared__ u32 rows[8];
    __shared__ u32 tasks[80];
    __shared__ u32 tcnt;
    __shared__ int rdds[20];

    const int t = threadIdx.x;
    const int lane = t & 63;
    const u32 cnt = gcnt[0];
    if (t < 20) rdds[t] = rdd[t];

    for (u32 base = blockIdx.x * 8; base < cnt; base += gridDim.x * 8) {
        const int R = (int)min(8u, cnt - base);
        __syncthreads();
        if (t < R) rows[t] = glist[base + t];
        if (t == 0) tcnt = 0;
        for (int i = t; i < 160; i += 512) {
            if (i < 80) ((float*)lgx)[i] = 0.f;
            else        ((float*)oax)[i - 80] = 0.f;
        }
        __syncthreads();
        // stage the flagged rows of x
        for (int i = t; i < R * 64; i += 512) {
            int r = i >> 6, c4 = i & 63;
            *(float4*)&xs[r][c4 * 4] =
                *(const float4*)(x + (size_t)rows[r] * 256 + c4 * 4);
        }
        __syncthreads();
        // exact target-net: thread t = hidden unit n (coalesced Wt1 columns)
        float ha[8] = {0.f,0.f,0.f,0.f,0.f,0.f,0.f,0.f};
        for (int k = 0; k < 256; ++k) {
            float wv = Wt1[(size_t)k * 512 + t];
            #pragma unroll
            for (int r = 0; r < 8; ++r) ha[r] += xs[r][k] * wv;
        }
        float bv = bt1[t];
        #pragma unroll
        for (int r = 0; r < 8; ++r) { float h = ha[r] + bv; ha[r] = h > 0.f ? h : 0.f; }
        #pragma unroll
        for (int r = 0; r < 8; ++r) {
            if (r < R) {
                float pr[10];
                #pragma unroll
                for (int c = 0; c < 10; ++c) pr[c] = ha[r] * wt2t[c * 512 + t];
                #pragma unroll
                for (int c = 0; c < 10; ++c) {
                    float v = pr[c];
                    v += __shfl_xor(v, 1, 64);  v += __shfl_xor(v, 2, 64);
                    v += __shfl_xor(v, 4, 64);  v += __shfl_xor(v, 8, 64);
                    v += __shfl_xor(v, 16, 64); v += __shfl_xor(v, 32, 64);
                    pr[c] = v;
                }
                if (lane == 0)
                    #pragma unroll
                    for (int c = 0; c < 10; ++c) atomicAdd(&lgx[r][c], pr[c]);
            }
        }
        __syncthreads();
        // exact bitmap + task list
        if (t < R) {
            float l[10];
            #pragma unroll
            for (int c = 0; c < 10; ++c) { l[c] = lgx[t][c] + bt2[c]; lgx[t][c] = l[c]; }
            float b0 = -1e30f; int i0 = 0;
            #pragma unroll
            for (int c = 0; c < 10; ++c) if (l[c] > b0) { b0 = l[c]; i0 = c; }
            float b1 = -1e30f; int i1 = 0;
            #pragma unroll
            for (int c = 0; c < 10; ++c) { if (c == i0) continue; if (l[c] > b1) { b1 = l[c]; i1 = c; } }
            u32 exact = 0, fb = 0;
            #pragma unroll
            for (int p = 0; p < 10; ++p) {
                int a = rdds[2 * p], bq = rdds[2 * p + 1];
                if (i0 == a && i1 == bq) exact |= 1u << p;
                if (i0 == a)             fb    |= 1u << p;
            }
            u32 bits = exact ? exact : fb;
            while (bits) {
                int p = __ffs(bits) - 1;
                bits &= bits - 1;
                u32 e = atomicAdd(&tcnt, 1u);
                tasks[e] = ((u32)t << 4) | (u32)p;
            }
        }
        __syncthreads();
        // exact patch nets: 4 groups of 128 threads; thread tl = hidden unit
        {
            const int g = t >> 7, tl = t & 127;
            const u32 tc = tcnt;
            for (u32 ti = g; ti < tc; ti += 4) {
                int r = (int)(tasks[ti] >> 4), p = (int)(tasks[ti] & 15);
                float hp = 0.f;
                for (int k = 0; k < 256; ++k)
                    hp += xs[r][k] * Wp1[(size_t)p * 32768 + (size_t)k * 128 + tl];
                hp += bp1[p * 128 + tl]; hp = hp > 0.f ? hp : 0.f;
                float pr[10];
                #pragma unroll
                for (int c = 0; c < 10; ++c) pr[c] = hp * wp2t[p * 1280 + c * 128 + tl];
                #pragma unroll
                for (int c = 0; c < 10; ++c) {
                    float v = pr[c];
                    v += __shfl_xor(v, 1, 64);  v += __shfl_xor(v, 2, 64);
                    v += __shfl_xor(v, 4, 64);  v += __shfl_xor(v, 8, 64);
                    v += __shfl_xor(v, 16, 64); v += __shfl_xor(v, 32, 64);
                    pr[c] = v;
                }
                if ((t & 63) == 0) {
                    #pragma unroll
                    for (int c = 0; c < 10; ++c)
                        atomicAdd(&oax[r][c], pr[c] + ((tl == 0) ? bp2[p * 10 + c] : 0.f));
                }
            }
        }
        __syncthreads();
        if (t < R * 10) {
            int r = t / 10, c = t % 10;
            out[(size_t)rows[r] * 10 + c] = lgx[r][c] + oax[r][c];
        }
    }
}

extern "C" void kernel_launch(void* const* d_in, const int* in_sizes, int n_in,
                              void* d_out, int out_size, void* d_ws, size_t ws_size,
                              hipStream_t stream) {
    const float* x   = (const float*)d_in[0];
    const float* Wt1 = (const float*)d_in[1];
    const float* bt1 = (const float*)d_in[2];
    const float* Wt2 = (const float*)d_in[3];
    const float* bt2 = (const float*)d_in[4];
    const float* Wp1 = (const float*)d_in[5];
    const float* bp1 = (const float*)d_in[6];
    const float* Wp2 = (const float*)d_in[7];
    const float* bp2 = (const float*)d_in[8];
    const int* rdd = (const int*)d_in[9];
    float* out = (float*)d_out;

    u16* wt1f = (u16*)d_ws;                 // 131072 u16
    u16* wp1f = wt1f + 131072;              // 327680 u16
    u16* wt2f = wp1f + 327680;              // 8192 u16
    u16* wp2f = wt2f + 8192;                // 20480 u16
    float* wt2t = (float*)(wp2f + 20480);   // 5120 f32
    float* wp2t = wt2t + 5120;              // 12800 f32
    u32* gcnt  = (u32*)(wp2t + 12800);      // 1 (+pad to 16)
    u32* glist = gcnt + 16;                 // 65536 u32

    hipLaunchKernelGGL(conv_kernel, dim3(113), dim3(256), 0, stream,
                       Wt1, Wp1, Wt2, Wp2, wt1f, wp1f, wt2f, wp2f, wt2t, wp2t, gcnt);
    hipLaunchKernelGGL(netsum_kernel, dim3(1024), dim3(512), 0, stream,
                       x, bt1, bt2, bp1, bp2, rdd,
                       wt1f, wp1f, wt2f, wp2f, out, gcnt, glist);
    hipLaunchKernelGGL(fix_kernel, dim3(512), dim3(512), 0, stream,
                       x, Wt1, bt1, bt2, Wp1, bp1, bp2, rdd, wt2t, wp2t,
                       gcnt, glist, out);
}

// Round 3
// 215.252 us; speedup vs baseline: 1.9391x; 1.4375x over previous
//
#include <hip/hip_runtime.h>

typedef unsigned int u32;
typedef unsigned short u16;
typedef _Float16 f16;
typedef __attribute__((ext_vector_type(8))) _Float16 f16x8;
typedef __attribute__((ext_vector_type(4))) float f32x4;

#define MARGIN 1e-2f
#define LSC 2048.0f          // lo-split scale (keeps lo terms normal in f16)
#define LSCI (1.0f/2048.0f)

__device__ __forceinline__ u16 f16b(float f) {
    return __builtin_bit_cast(u16, (f16)f);
}
__device__ __forceinline__ f32x4 MF(f16x8 a, f16x8 b, f32x4 c) {
    return __builtin_amdgcn_mfma_f32_16x16x32_f16(a, b, c, 0, 0, 0);
}
__device__ __forceinline__ uint4 pack8(const u16 v[8]) {
    uint4 pk;
    pk.x = (u32)v[0] | ((u32)v[1] << 16);
    pk.y = (u32)v[2] | ((u32)v[3] << 16);
    pk.z = (u32)v[4] | ((u32)v[5] << 16);
    pk.w = (u32)v[6] | ((u32)v[7] << 16);
    return pk;
}

// ---------------------------------------------------------------------------
// conv: weights -> f16 MFMA-fragment-linear layouts (hi + scaled-lo for the
// exact-fix path). frag(nf,kk) of [K x N]: lane l (ln=l&15, quad=l>>4) holds
// 8 f16 = W[kk*32+quad*8+j][nf*16+ln], at (nf*8+kk)*512 + l*8 (u16 units).
// blocks 0..31: Wt1 -> wt1f (hi) + wt1g (2048*lo)
// blocks 32..111: Wp1 per p -> wp1f (hi only)
// block 112: wt2f/wt2g (K=512, C pad 16), wp2f (hi, K=128), gcnt=0
// ---------------------------------------------------------------------------
__global__ __launch_bounds__(256) void conv_kernel(
    const float* __restrict__ Wt1, const float* __restrict__ Wp1,
    const float* __restrict__ Wt2, const float* __restrict__ Wp2,
    u16* __restrict__ wt1f, u16* __restrict__ wt1g, u16* __restrict__ wp1f,
    u16* __restrict__ wt2f, u16* __restrict__ wt2g, u16* __restrict__ wp2f,
    u32* __restrict__ gcnt)
{
    __shared__ float tile[64][68];
    const int t = threadIdx.x;
    const int b = blockIdx.x;

    if (b == 112) {
        if (t == 0) gcnt[0] = 0;
        // wt2f/wt2g: 16 kk-frags of Wt2 [512 x 10->16]
        for (int cc = t; cc < 1024; cc += 256) {
            int kk = cc >> 6, l = cc & 63, ln = l & 15, quad = l >> 4;
            u16 vh[8], vl[8];
            #pragma unroll
            for (int j = 0; j < 8; ++j) {
                int k = kk * 32 + quad * 8 + j;
                float f = (ln < 10) ? Wt2[k * 10 + ln] : 0.f;
                f16 h = (f16)f;
                vh[j] = __builtin_bit_cast(u16, h);
                vl[j] = f16b(LSC * (f - (float)h));
            }
            *(uint4*)(wt2f + kk * 512 + l * 8) = pack8(vh);
            *(uint4*)(wt2g + kk * 512 + l * 8) = pack8(vl);
        }
        // wp2f: per p, 4 kk-frags of Wp2[p] [128 x 10->16] (hi only)
        for (int cc = t; cc < 2560; cc += 256) {
            int p = cc >> 8, rem = cc & 255, kk = rem >> 6, l = rem & 63;
            int ln = l & 15, quad = (l >> 4) & 3;
            u16 v[8];
            #pragma unroll
            for (int j = 0; j < 8; ++j) {
                int k = kk * 32 + quad * 8 + j;
                v[j] = f16b(ln < 10 ? Wp2[p * 1280 + k * 10 + ln] : 0.f);
            }
            *(uint4*)(wp2f + p * 2048 + kk * 512 + l * 8) = pack8(v);
        }
        return;
    }

    const float* src; int src_ld;
    u16 *dsth, *dstl; int nf0, kk0;
    if (b < 32) {
        int kt = b & 3, nt = b >> 2;
        src = Wt1 + (size_t)(kt * 64) * 512 + nt * 64; src_ld = 512;
        dsth = wt1f; dstl = wt1g; nf0 = nt * 4; kk0 = kt * 2;
    } else {
        int j = b - 32, p = j >> 3, r = j & 7;
        int kt = r & 3, nt = r >> 2;
        src = Wp1 + (size_t)p * 32768 + (size_t)(kt * 64) * 128 + nt * 64; src_ld = 128;
        dsth = wp1f + p * 32768; dstl = nullptr; nf0 = nt * 4; kk0 = kt * 2;
    }
    {
        const int kr = t >> 2, c0 = (t & 3) * 16;
        #pragma unroll
        for (int u = 0; u < 4; ++u) {
            float4 v = *(const float4*)(src + (size_t)kr * src_ld + c0 + u * 4);
            tile[kr][c0 + u*4 + 0] = v.x;
            tile[kr][c0 + u*4 + 1] = v.y;
            tile[kr][c0 + u*4 + 2] = v.z;
            tile[kr][c0 + u*4 + 3] = v.w;
        }
    }
    __syncthreads();
    #pragma unroll
    for (int s = 0; s < 2; ++s) {
        int cc = t + 256 * s;              // 512 chunks per 64x64 tile
        int l = cc & 63, fp = cc >> 6, nfl = fp >> 1, kkl = fp & 1;
        int ln = l & 15, quad = (l >> 4) & 3;
        int nloc = nfl * 16 + ln, kloc = kkl * 32 + quad * 8;
        u16 vh[8], vl[8];
        #pragma unroll
        for (int j = 0; j < 8; ++j) {
            float f = tile[kloc + j][nloc];
            f16 h = (f16)f;
            vh[j] = __builtin_bit_cast(u16, h);
            vl[j] = f16b(LSC * (f - (float)h));
        }
        size_t off = (size_t)((nf0 + nfl) * 8 + (kk0 + kkl)) * 512 + l * 8;
        *(uint4*)(dsth + off) = pack8(vh);
        if (dstl) *(uint4*)(dstl + off) = pack8(vl);
    }
}

// ---------------------------------------------------------------------------
// netsum: per 64-row block: stage x->f16 LDS; layer1 f16 MFMA (n in 2 halves,
// h -> LDS); layer2 via MFMA; margin rows -> global list (fixed by fix_kernel);
// bitmap + gated patch nets fully in MFMA (per-wave h_p scratch in hbuf).
// ---------------------------------------------------------------------------
__global__ __launch_bounds__(512, 4) void netsum_kernel(
    const float* __restrict__ x, const float* __restrict__ bt1,
    const float* __restrict__ bt2,
    const float* __restrict__ bp1, const float* __restrict__ bp2,
    const int* __restrict__ rdd,
    const u16* __restrict__ wt1f, const u16* __restrict__ wp1f,
    const u16* __restrict__ wt2f, const u16* __restrict__ wp2f,
    float* __restrict__ out, u32* __restrict__ gcnt, u32* __restrict__ glist)
{
    __shared__ u16 xf[64][264];      // 33792 B  (x in f16, row stride 528B)
    __shared__ u16 hbuf[17408];      // 34816 B  h-half [64][264] / patch hp 8x2176
    __shared__ float lg[64][10];
    __shared__ float oacc[64][10];
    __shared__ u32 plist[10][64];
    __shared__ u32 pcnt[10];
    __shared__ int rdds[20];
    __shared__ u32 wq[40];
    __shared__ u32 nwork;
    // total ~76.5 KB -> 2 blocks/CU

    const int t = threadIdx.x;
    const int lane = t & 63;
    const int w = t >> 6;
    const int ln = lane & 15;
    const int quad = lane >> 4;
    const int row0 = blockIdx.x * 64;

    if (t < 10) pcnt[t] = 0;
    if (t < 20) rdds[t] = rdd[t];
    if (t == 0) nwork = 0;
    for (int i = t; i < 640; i += 512) ((float*)oacc)[i] = 0.f;

    // ---- stage x -> f16 LDS (coalesced) ----
    #pragma unroll
    for (int i = 0; i < 8; ++i) {
        int f = t + 512 * i;           // float4 index 0..4095
        int r = f >> 6, c4 = f & 63;
        float4 v = *(const float4*)(x + (size_t)(row0 + r) * 256 + c4 * 4);
        u16 q0 = f16b(v.x), q1 = f16b(v.y), q2 = f16b(v.z), q3 = f16b(v.w);
        uint2 pw = { (u32)q0 | ((u32)q1 << 16), (u32)q2 | ((u32)q3 << 16) };
        *(uint2*)&xf[r][c4 * 4] = pw;
    }
    __syncthreads();

    // ---- layer 1 (f16 MFMA, coalesced frag-linear B) + layer 2 (MFMA) ----
    f32x4 acc2 = (f32x4){0.f, 0.f, 0.f, 0.f};   // layer-2 accum (waves 0..3)
    for (int hl = 0; hl < 2; ++hl) {
        f32x4 acc[4][2];
        #pragma unroll
        for (int m = 0; m < 4; ++m) {
            acc[m][0] = (f32x4){0.f,0.f,0.f,0.f};
            acc[m][1] = (f32x4){0.f,0.f,0.f,0.f};
        }
        // wave w owns n = hl*256 + w*32 + i2*16 + ln
        const u16* bb = wt1f + (size_t)(hl * 16 + w * 2) * 4096 + lane * 8;
        for (int kk = 0; kk < 8; ++kk) {
            f16x8 b0 = *(const f16x8*)(bb + kk * 512);
            f16x8 b1 = *(const f16x8*)(bb + 4096 + kk * 512);
            #pragma unroll
            for (int m = 0; m < 4; ++m) {
                f16x8 a = *(const f16x8*)(&xf[m * 16 + ln][kk * 32 + quad * 8]);
                acc[m][0] = MF(a, b0, acc[m][0]);
                acc[m][1] = MF(a, b1, acc[m][1]);
            }
        }
        // bias + relu + f16 -> hbuf [64][264]
        #pragma unroll
        for (int m = 0; m < 4; ++m)
            #pragma unroll
            for (int i2 = 0; i2 < 2; ++i2) {
                int nloc = w * 32 + i2 * 16 + ln;
                float bias = bt1[hl * 256 + nloc];
                #pragma unroll
                for (int r = 0; r < 4; ++r) {
                    float hv = acc[m][i2][r] + bias; hv = hv > 0.f ? hv : 0.f;
                    hbuf[(m * 16 + quad * 4 + r) * 264 + nloc] = f16b(hv);
                }
            }
        __syncthreads();
        // layer 2: waves 0..3, wave w = m-frag w, K=256 per half
        if (w < 4) {
            #pragma unroll
            for (int kk = 0; kk < 8; ++kk) {
                f16x8 ha = *(const f16x8*)(&hbuf[(w * 16 + ln) * 264 + kk * 32 + quad * 8]);
                f16x8 wb = *(const f16x8*)(wt2f + (hl * 8 + kk) * 512 + lane * 8);
                acc2 = MF(ha, wb, acc2);
            }
        }
        __syncthreads();   // before next half overwrites hbuf
    }
    if (w < 4 && ln < 10) {
        #pragma unroll
        for (int r = 0; r < 4; ++r)
            lg[w * 16 + quad * 4 + r][ln] = acc2[r] + bt2[ln];
    }
    __syncthreads();

    // ---- margin flag (-> global list) + bitmap + per-patch row lists ----
    if (t < 64) {
        float l[10];
        #pragma unroll
        for (int c = 0; c < 10; ++c) l[c] = lg[t][c];
        float b0 = -1e30f; int i0 = 0;
        #pragma unroll
        for (int c = 0; c < 10; ++c) if (l[c] > b0) { b0 = l[c]; i0 = c; }
        float b1 = -1e30f; int i1 = 0;
        #pragma unroll
        for (int c = 0; c < 10; ++c) { if (c == i0) continue; if (l[c] > b1) { b1 = l[c]; i1 = c; } }
        float b2v = -1e30f;
        #pragma unroll
        for (int c = 0; c < 10; ++c) { if (c == i0 || c == i1) continue; if (l[c] > b2v) b2v = l[c]; }
        if (b0 - b1 < MARGIN || b1 - b2v < MARGIN) {
            u32 idx = atomicAdd(gcnt, 1u);
            glist[idx] = (u32)(row0 + t);
        }
        u32 exact = 0, fb = 0;
        #pragma unroll
        for (int p = 0; p < 10; ++p) {
            int a = rdds[2 * p], bq = rdds[2 * p + 1];
            if (i0 == a && i1 == bq) exact |= 1u << p;
            if (i0 == a)             fb    |= 1u << p;
        }
        u32 bits = exact ? exact : fb;
        while (bits) {
            int p = __ffs(bits) - 1;
            bits &= bits - 1;
            u32 idx = atomicAdd(&pcnt[p], 1u);
            plist[p][idx] = (u32)t;
        }
    }
    __syncthreads();
    if (t < 10) {
        int L = (int)pcnt[t];
        for (int base = 0; base < L; base += 16) {
            u32 e = atomicAdd(&nwork, 1u);
            wq[e] = ((u32)t << 8) | (u32)base;
        }
    }
    __syncthreads();

    // ---- gated patch nets: f16 MFMA layer1 + MFMA layer2 (per-wave hp) ----
    {
        const u32 nw = nwork;
        for (u32 ii = w; ii < nw; ii += 8) {
            const u32 item = wq[ii];
            const int p = (int)(item >> 8), mbase = (int)(item & 255);
            const int Lp = (int)pcnt[p];
            const int mi = mbase + ln;
            const int arow = (mi < Lp) ? (int)plist[p][mi] : (int)plist[p][0];
            const u16* xr = &xf[arow][0];
            const u16* wb = wp1f + (size_t)p * 32768 + lane * 8;
            f32x4 pacc[8];
            #pragma unroll
            for (int i2 = 0; i2 < 8; ++i2) pacc[i2] = (f32x4){0.f,0.f,0.f,0.f};
            for (int kk = 0; kk < 8; ++kk) {
                f16x8 a = *(const f16x8*)(xr + kk * 32 + quad * 8);
                #pragma unroll
                for (int i2 = 0; i2 < 8; ++i2) {
                    f16x8 bb2 = *(const f16x8*)(wb + (i2 * 8 + kk) * 512);
                    pacc[i2] = MF(a, bb2, pacc[i2]);
                }
            }
            // hp: [16][136] per-wave scratch (row stride 272B)
            u16* hp = &hbuf[w * 2176];
            #pragma unroll
            for (int i2 = 0; i2 < 8; ++i2) {
                float bias = bp1[p * 128 + i2 * 16 + ln];
                #pragma unroll
                for (int r = 0; r < 4; ++r) {
                    float hv = pacc[i2][r] + bias; hv = hv > 0.f ? hv : 0.f;
                    hp[(quad * 4 + r) * 136 + i2 * 16 + ln] = f16b(hv);
                }
            }
            f32x4 po = (f32x4){0.f,0.f,0.f,0.f};
            #pragma unroll
            for (int kk = 0; kk < 4; ++kk) {
                f16x8 ha = *(const f16x8*)(&hp[ln * 136 + kk * 32 + quad * 8]);
                f16x8 wb2 = *(const f16x8*)(wp2f + p * 2048 + kk * 512 + lane * 8);
                po = MF(ha, wb2, po);
            }
            if (ln < 10) {
                float b2 = bp2[p * 10 + ln];
                #pragma unroll
                for (int r = 0; r < 4; ++r) {
                    int mi2 = mbase + quad * 4 + r;
                    if (mi2 < Lp)
                        atomicAdd(&oacc[plist[p][mi2]][ln], po[r] + b2);
                }
            }
        }
    }
    __syncthreads();

    for (int i = t; i < 640; i += 512)
        out[(size_t)row0 * 10 + i] = ((float*)lg)[i] + ((float*)oacc)[i];
}

// ---------------------------------------------------------------------------
// fix: high-precision recompute for margin-flagged rows, MFMA throughout.
// Gathers 64 flagged rows/block; split-f16 (hi + 2048*lo, 3 MFMAs) layer1+2
// reproduces fp32 logits to ~1e-7 -> exact bitmap; patch nets plain f16 MFMA
// (values only; bitmap is independent of patches). Overwrites out[row].
// ---------------------------------------------------------------------------
__global__ __launch_bounds__(512, 1) void fix_kernel(
    const float* __restrict__ x, const float* __restrict__ bt1,
    const float* __restrict__ bt2,
    const float* __restrict__ bp1, const float* __restrict__ bp2,
    const int* __restrict__ rdd,
    const u16* __restrict__ wt1f, const u16* __restrict__ wt1g,
    const u16* __restrict__ wt2f, const u16* __restrict__ wt2g,
    const u16* __restrict__ wp1f, const u16* __restrict__ wp2f,
    const u32* __restrict__ gcnt, const u32* __restrict__ glist,
    float* __restrict__ out)
{
    __shared__ u16 xfh[64][264];     // 33792 B  x hi
    __shared__ u16 xfl[64][264];     // 33792 B  x scaled-lo
    __shared__ u16 hb2[2][16896];    // 67584 B  h hi/lo halves; [0] reused as hp
    __shared__ float lg[64][10];
    __shared__ float oacc[64][10];
    __shared__ u32 rows[64];
    __shared__ u32 plist[10][64];
    __shared__ u32 pcnt[10];
    __shared__ int rdds[20];
    __shared__ u32 wq[40];
    __shared__ u32 nwork;
    // ~143 KB -> 1 block/CU

    const int t = threadIdx.x;
    const int lane = t & 63;
    const int w = t >> 6;
    const int ln = lane & 15;
    const int quad = lane >> 4;
    const u32 cnt = gcnt[0];
    if (t < 20) rdds[t] = rdd[t];

    for (u32 base = blockIdx.x * 64; base < cnt; base += gridDim.x * 64) {
        __syncthreads();                       // protect buffers from prev iter
        const int R = (int)min(64u, cnt - base);
        if (t < 64) rows[t] = glist[base + (t < R ? t : 0)];
        if (t < 10) pcnt[t] = 0;
        if (t == 0) nwork = 0;
        for (int i = t; i < 640; i += 512) ((float*)oacc)[i] = 0.f;
        __syncthreads();

        // ---- gather flagged x rows -> hi/lo f16 LDS ----
        #pragma unroll
        for (int i = 0; i < 8; ++i) {
            int f = t + 512 * i;
            int r = f >> 6, c4 = f & 63;
            float4 v = *(const float4*)(x + (size_t)rows[r] * 256 + c4 * 4);
            f16 h0 = (f16)v.x, h1 = (f16)v.y, h2 = (f16)v.z, h3 = (f16)v.w;
            u16 q0 = __builtin_bit_cast(u16, h0), q1 = __builtin_bit_cast(u16, h1);
            u16 q2 = __builtin_bit_cast(u16, h2), q3 = __builtin_bit_cast(u16, h3);
            u16 l0 = f16b(LSC * (v.x - (float)h0)), l1 = f16b(LSC * (v.y - (float)h1));
            u16 l2 = f16b(LSC * (v.z - (float)h2)), l3 = f16b(LSC * (v.w - (float)h3));
            uint2 hw = { (u32)q0 | ((u32)q1 << 16), (u32)q2 | ((u32)q3 << 16) };
            uint2 lw = { (u32)l0 | ((u32)l1 << 16), (u32)l2 | ((u32)l3 << 16) };
            *(uint2*)&xfh[r][c4 * 4] = hw;
            *(uint2*)&xfl[r][c4 * 4] = lw;
        }
        __syncthreads();

        // ---- layer 1 split-f16 (3 MFMA) + layer 2 split-f16 (3 MFMA) ----
        f32x4 acc2h = (f32x4){0.f,0.f,0.f,0.f};
        f32x4 acc2s = (f32x4){0.f,0.f,0.f,0.f};
        for (int hl = 0; hl < 2; ++hl) {
            f32x4 accH[4][2], accS[4][2];
            #pragma unroll
            for (int m = 0; m < 4; ++m)
                #pragma unroll
                for (int i2 = 0; i2 < 2; ++i2) {
                    accH[m][i2] = (f32x4){0.f,0.f,0.f,0.f};
                    accS[m][i2] = (f32x4){0.f,0.f,0.f,0.f};
                }
            const size_t boff = (size_t)(hl * 16 + w * 2) * 4096 + lane * 8;
            const u16* bbh = wt1f + boff;
            const u16* bbl = wt1g + boff;
            for (int kk = 0; kk < 8; ++kk) {
                f16x8 bh0 = *(const f16x8*)(bbh + kk * 512);
                f16x8 bh1 = *(const f16x8*)(bbh + 4096 + kk * 512);
                f16x8 bl0 = *(const f16x8*)(bbl + kk * 512);
                f16x8 bl1 = *(const f16x8*)(bbl + 4096 + kk * 512);
                #pragma unroll
                for (int m = 0; m < 4; ++m) {
                    f16x8 ah = *(const f16x8*)(&xfh[m * 16 + ln][kk * 32 + quad * 8]);
                    f16x8 al = *(const f16x8*)(&xfl[m * 16 + ln][kk * 32 + quad * 8]);
                    accH[m][0] = MF(ah, bh0, accH[m][0]);
                    accS[m][0] = MF(ah, bl0, accS[m][0]);
                    accS[m][0] = MF(al, bh0, accS[m][0]);
                    accH[m][1] = MF(ah, bh1, accH[m][1]);
                    accS[m][1] = MF(ah, bl1, accS[m][1]);
                    accS[m][1] = MF(al, bh1, accS[m][1]);
                }
            }
            // bias + relu + hi/lo split -> hb2
            #pragma unroll
            for (int m = 0; m < 4; ++m)
                #pragma unroll
                for (int i2 = 0; i2 < 2; ++i2) {
                    int nloc = w * 32 + i2 * 16 + ln;
                    float bias = bt1[hl * 256 + nloc];
                    #pragma unroll
                    for (int r = 0; r < 4; ++r) {
                        float hv = accH[m][i2][r] + accS[m][i2][r] * LSCI + bias;
                        hv = hv > 0.f ? hv : 0.f;
                        f16 hh = (f16)hv;
                        int idx = (m * 16 + quad * 4 + r) * 264 + nloc;
                        hb2[0][idx] = __builtin_bit_cast(u16, hh);
                        hb2[1][idx] = f16b(LSC * (hv - (float)hh));
                    }
                }
            __syncthreads();
            if (w < 4) {
                #pragma unroll
                for (int kk = 0; kk < 8; ++kk) {
                    int hidx = (w * 16 + ln) * 264 + kk * 32 + quad * 8;
                    f16x8 hah = *(const f16x8*)(&hb2[0][hidx]);
                    f16x8 hal = *(const f16x8*)(&hb2[1][hidx]);
                    f16x8 wbh = *(const f16x8*)(wt2f + (hl * 8 + kk) * 512 + lane * 8);
                    f16x8 wbl = *(const f16x8*)(wt2g + (hl * 8 + kk) * 512 + lane * 8);
                    acc2h = MF(hah, wbh, acc2h);
                    acc2s = MF(hah, wbl, acc2s);
                    acc2s = MF(hal, wbh, acc2s);
                }
            }
            __syncthreads();
        }
        if (w < 4 && ln < 10) {
            #pragma unroll
            for (int r = 0; r < 4; ++r)
                lg[w * 16 + quad * 4 + r][ln] = acc2h[r] + acc2s[r] * LSCI + bt2[ln];
        }
        __syncthreads();

        // ---- exact bitmap + per-patch row lists ----
        if (t < R) {
            float l[10];
            #pragma unroll
            for (int c = 0; c < 10; ++c) l[c] = lg[t][c];
            float b0 = -1e30f; int i0 = 0;
            #pragma unroll
            for (int c = 0; c < 10; ++c) if (l[c] > b0) { b0 = l[c]; i0 = c; }
            float b1 = -1e30f; int i1 = 0;
            #pragma unroll
            for (int c = 0; c < 10; ++c) { if (c == i0) continue; if (l[c] > b1) { b1 = l[c]; i1 = c; } }
            u32 exact = 0, fb = 0;
            #pragma unroll
            for (int p = 0; p < 10; ++p) {
                int a = rdds[2 * p], bq = rdds[2 * p + 1];
                if (i0 == a && i1 == bq) exact |= 1u << p;
                if (i0 == a)             fb    |= 1u << p;
            }
            u32 bits = exact ? exact : fb;
            while (bits) {
                int p = __ffs(bits) - 1;
                bits &= bits - 1;
                u32 idx = atomicAdd(&pcnt[p], 1u);
                plist[p][idx] = (u32)t;
            }
        }
        __syncthreads();
        if (t < 10) {
            int L = (int)pcnt[t];
            for (int b2 = 0; b2 < L; b2 += 16) {
                u32 e = atomicAdd(&nwork, 1u);
                wq[e] = ((u32)t << 8) | (u32)b2;
            }
        }
        __syncthreads();

        // ---- patch nets: plain f16 MFMA (same as netsum) ----
        {
            const u32 nw = nwork;
            u16* hbuf = &hb2[0][0];
            for (u32 ii = w; ii < nw; ii += 8) {
                const u32 item = wq[ii];
                const int p = (int)(item >> 8), mbase = (int)(item & 255);
                const int Lp = (int)pcnt[p];
                const int mi = mbase + ln;
                const int arow = (mi < Lp) ? (int)plist[p][mi] : (int)plist[p][0];
                const u16* xr = &xfh[arow][0];
                const u16* wb = wp1f + (size_t)p * 32768 + lane * 8;
                f32x4 pacc[8];
                #pragma unroll
                for (int i2 = 0; i2 < 8; ++i2) pacc[i2] = (f32x4){0.f,0.f,0.f,0.f};
                for (int kk = 0; kk < 8; ++kk) {
                    f16x8 a = *(const f16x8*)(xr + kk * 32 + quad * 8);
                    #pragma unroll
                    for (int i2 = 0; i2 < 8; ++i2) {
                        f16x8 bb2 = *(const f16x8*)(wb + (i2 * 8 + kk) * 512);
                        pacc[i2] = MF(a, bb2, pacc[i2]);
                    }
                }
                u16* hp = &hbuf[w * 2176];
                #pragma unroll
                for (int i2 = 0; i2 < 8; ++i2) {
                    float bias = bp1[p * 128 + i2 * 16 + ln];
                    #pragma unroll
                    for (int r = 0; r < 4; ++r) {
                        float hv = pacc[i2][r] + bias; hv = hv > 0.f ? hv : 0.f;
                        hp[(quad * 4 + r) * 136 + i2 * 16 + ln] = f16b(hv);
                    }
                }
                f32x4 po = (f32x4){0.f,0.f,0.f,0.f};
                #pragma unroll
                for (int kk = 0; kk < 4; ++kk) {
                    f16x8 ha = *(const f16x8*)(&hp[ln * 136 + kk * 32 + quad * 8]);
                    f16x8 wb2 = *(const f16x8*)(wp2f + p * 2048 + kk * 512 + lane * 8);
                    po = MF(ha, wb2, po);
                }
                if (ln < 10) {
                    float b2 = bp2[p * 10 + ln];
                    #pragma unroll
                    for (int r = 0; r < 4; ++r) {
                        int mi2 = mbase + quad * 4 + r;
                        if (mi2 < Lp)
                            atomicAdd(&oacc[plist[p][mi2]][ln], po[r] + b2);
                    }
                }
            }
        }
        __syncthreads();

        for (int i = t; i < R * 10; i += 512) {
            int r = i / 10, c = i % 10;
            out[(size_t)rows[r] * 10 + c] = lg[r][c] + oacc[r][c];
        }
    }
}

extern "C" void kernel_launch(void* const* d_in, const int* in_sizes, int n_in,
                              void* d_out, int out_size, void* d_ws, size_t ws_size,
                              hipStream_t stream) {
    const float* x   = (const float*)d_in[0];
    const float* Wt1 = (const float*)d_in[1];
    const float* bt1 = (const float*)d_in[2];
    const float* Wt2 = (const float*)d_in[3];
    const float* bt2 = (const float*)d_in[4];
    const float* Wp1 = (const float*)d_in[5];
    const float* bp1 = (const float*)d_in[6];
    const float* Wp2 = (const float*)d_in[7];
    const float* bp2 = (const float*)d_in[8];
    const int* rdd = (const int*)d_in[9];
    float* out = (float*)d_out;

    u16* wt1f = (u16*)d_ws;                 // 131072 u16
    u16* wt1g = wt1f + 131072;              // 131072 u16
    u16* wp1f = wt1g + 131072;              // 327680 u16
    u16* wt2f = wp1f + 327680;              // 8192 u16
    u16* wt2g = wt2f + 8192;                // 8192 u16
    u16* wp2f = wt2g + 8192;                // 20480 u16
    u32* gcnt  = (u32*)(wp2f + 20480);      // 1 (+pad to 16)
    u32* glist = gcnt + 16;                 // 65536 u32

    hipLaunchKernelGGL(conv_kernel, dim3(113), dim3(256), 0, stream,
                       Wt1, Wp1, Wt2, Wp2, wt1f, wt1g, wp1f, wt2f, wt2g, wp2f, gcnt);
    hipLaunchKernelGGL(netsum_kernel, dim3(1024), dim3(512), 0, stream,
                       x, bt1, bt2, bp1, bp2, rdd,
                       wt1f, wp1f, wt2f, wp2f, out, gcnt, glist);
    hipLaunchKernelGGL(fix_kernel, dim3(128), dim3(512), 0, stream,
                       x, bt1, bt2, bp1, bp2, rdd,
                       wt1f, wt1g, wt2f, wt2g, wp1f, wp2f,
                       gcnt, glist, out);
}

// Round 4
// 207.899 us; speedup vs baseline: 2.0076x; 1.0354x over previous
//
#include <hip/hip_runtime.h>

typedef unsigned int u32;
typedef unsigned short u16;
typedef _Float16 f16;
typedef __attribute__((ext_vector_type(8))) _Float16 f16x8;
typedef __attribute__((ext_vector_type(4))) float f32x4;

#define MARGIN 1e-2f
#define LSC 2048.0f          // lo-split scale (keeps lo terms normal in f16)
#define LSCI (1.0f/2048.0f)

__device__ __forceinline__ u16 f16b(float f) {
    return __builtin_bit_cast(u16, (f16)f);
}
__device__ __forceinline__ f32x4 MF(f16x8 a, f16x8 b, f32x4 c) {
    return __builtin_amdgcn_mfma_f32_16x16x32_f16(a, b, c, 0, 0, 0);
}
__device__ __forceinline__ uint4 pack8(const u16 v[8]) {
    uint4 pk;
    pk.x = (u32)v[0] | ((u32)v[1] << 16);
    pk.y = (u32)v[2] | ((u32)v[3] << 16);
    pk.z = (u32)v[4] | ((u32)v[5] << 16);
    pk.w = (u32)v[6] | ((u32)v[7] << 16);
    return pk;
}

// ---------------------------------------------------------------------------
// conv: weights -> f16 MFMA-fragment-linear layouts (hi + scaled-lo for the
// exact-fix path). frag(nf,kk) of [K x N]: lane l (ln=l&15, quad=l>>4) holds
// 8 f16 = W[kk*32+quad*8+j][nf*16+ln], at (nf*8+kk)*512 + l*8 (u16 units).
// ---------------------------------------------------------------------------
__global__ __launch_bounds__(256) void conv_kernel(
    const float* __restrict__ Wt1, const float* __restrict__ Wp1,
    const float* __restrict__ Wt2, const float* __restrict__ Wp2,
    u16* __restrict__ wt1f, u16* __restrict__ wt1g, u16* __restrict__ wp1f,
    u16* __restrict__ wt2f, u16* __restrict__ wt2g, u16* __restrict__ wp2f,
    u32* __restrict__ gcnt)
{
    __shared__ float tile[64][68];
    const int t = threadIdx.x;
    const int b = blockIdx.x;

    if (b == 112) {
        if (t == 0) gcnt[0] = 0;
        // wt2f/wt2g: 16 kk-frags of Wt2 [512 x 10->16]
        for (int cc = t; cc < 1024; cc += 256) {
            int kk = cc >> 6, l = cc & 63, ln = l & 15, quad = l >> 4;
            u16 vh[8], vl[8];
            #pragma unroll
            for (int j = 0; j < 8; ++j) {
                int k = kk * 32 + quad * 8 + j;
                float f = (ln < 10) ? Wt2[k * 10 + ln] : 0.f;
                f16 h = (f16)f;
                vh[j] = __builtin_bit_cast(u16, h);
                vl[j] = f16b(LSC * (f - (float)h));
            }
            *(uint4*)(wt2f + kk * 512 + l * 8) = pack8(vh);
            *(uint4*)(wt2g + kk * 512 + l * 8) = pack8(vl);
        }
        // wp2f: per p, 4 kk-frags of Wp2[p] [128 x 10->16] (hi only)
        for (int cc = t; cc < 2560; cc += 256) {
            int p = cc >> 8, rem = cc & 255, kk = rem >> 6, l = rem & 63;
            int ln = l & 15, quad = (l >> 4) & 3;
            u16 v[8];
            #pragma unroll
            for (int j = 0; j < 8; ++j) {
                int k = kk * 32 + quad * 8 + j;
                v[j] = f16b(ln < 10 ? Wp2[p * 1280 + k * 10 + ln] : 0.f);
            }
            *(uint4*)(wp2f + p * 2048 + kk * 512 + l * 8) = pack8(v);
        }
        return;
    }

    const float* src; int src_ld;
    u16 *dsth, *dstl; int nf0, kk0;
    if (b < 32) {
        int kt = b & 3, nt = b >> 2;
        src = Wt1 + (size_t)(kt * 64) * 512 + nt * 64; src_ld = 512;
        dsth = wt1f; dstl = wt1g; nf0 = nt * 4; kk0 = kt * 2;
    } else {
        int j = b - 32, p = j >> 3, r = j & 7;
        int kt = r & 3, nt = r >> 2;
        src = Wp1 + (size_t)p * 32768 + (size_t)(kt * 64) * 128 + nt * 64; src_ld = 128;
        dsth = wp1f + p * 32768; dstl = nullptr; nf0 = nt * 4; kk0 = kt * 2;
    }
    {
        const int kr = t >> 2, c0 = (t & 3) * 16;
        #pragma unroll
        for (int u = 0; u < 4; ++u) {
            float4 v = *(const float4*)(src + (size_t)kr * src_ld + c0 + u * 4);
            tile[kr][c0 + u*4 + 0] = v.x;
            tile[kr][c0 + u*4 + 1] = v.y;
            tile[kr][c0 + u*4 + 2] = v.z;
            tile[kr][c0 + u*4 + 3] = v.w;
        }
    }
    __syncthreads();
    #pragma unroll
    for (int s = 0; s < 2; ++s) {
        int cc = t + 256 * s;              // 512 chunks per 64x64 tile
        int l = cc & 63, fp = cc >> 6, nfl = fp >> 1, kkl = fp & 1;
        int ln = l & 15, quad = (l >> 4) & 3;
        int nloc = nfl * 16 + ln, kloc = kkl * 32 + quad * 8;
        u16 vh[8], vl[8];
        #pragma unroll
        for (int j = 0; j < 8; ++j) {
            float f = tile[kloc + j][nloc];
            f16 h = (f16)f;
            vh[j] = __builtin_bit_cast(u16, h);
            vl[j] = f16b(LSC * (f - (float)h));
        }
        size_t off = (size_t)((nf0 + nfl) * 8 + (kk0 + kkl)) * 512 + l * 8;
        *(uint4*)(dsth + off) = pack8(vh);
        if (dstl) *(uint4*)(dstl + off) = pack8(vl);
    }
}

// ---------------------------------------------------------------------------
// netsum: per 64-row block. B-fragments explicitly prefetched into registers
// (the round-3 kernel's 52-VGPR build serialized 16 L2 loads per wave per
// half -> ~4800 stall cycles; prefetch collapses that to ~1 stall).
// ---------------------------------------------------------------------------
__global__ __launch_bounds__(512, 4) void netsum_kernel(
    const float* __restrict__ x, const float* __restrict__ bt1,
    const float* __restrict__ bt2,
    const float* __restrict__ bp1, const float* __restrict__ bp2,
    const int* __restrict__ rdd,
    const u16* __restrict__ wt1f, const u16* __restrict__ wp1f,
    const u16* __restrict__ wt2f, const u16* __restrict__ wp2f,
    float* __restrict__ out, u32* __restrict__ gcnt, u32* __restrict__ glist)
{
    __shared__ u16 xf[64][264];      // 33792 B  (x in f16, row stride 528B)
    __shared__ u16 hbuf[17408];      // 34816 B  h-half [64][264] / patch hp 8x2176
    __shared__ float lg[64][10];
    __shared__ float oacc[64][10];
    __shared__ u32 plist[10][64];
    __shared__ u32 pcnt[10];
    __shared__ int rdds[20];
    __shared__ u32 wq[40];
    __shared__ u32 nwork;
    // total ~76.5 KB -> 2 blocks/CU

    const int t = threadIdx.x;
    const int lane = t & 63;
    const int w = t >> 6;
    const int ln = lane & 15;
    const int quad = lane >> 4;
    const int row0 = blockIdx.x * 64;

    if (t < 10) pcnt[t] = 0;
    if (t < 20) rdds[t] = rdd[t];
    if (t == 0) nwork = 0;
    for (int i = t; i < 640; i += 512) ((float*)oacc)[i] = 0.f;

    // ---- stage x -> f16 LDS (loads batched first, then convert+store) ----
    {
        float4 v[8];
        #pragma unroll
        for (int i = 0; i < 8; ++i) {
            int f = t + 512 * i;           // float4 index 0..4095
            int r = f >> 6, c4 = f & 63;
            v[i] = *(const float4*)(x + (size_t)(row0 + r) * 256 + c4 * 4);
        }
        #pragma unroll
        for (int i = 0; i < 8; ++i) {
            int f = t + 512 * i;
            int r = f >> 6, c4 = f & 63;
            u16 q0 = f16b(v[i].x), q1 = f16b(v[i].y), q2 = f16b(v[i].z), q3 = f16b(v[i].w);
            uint2 pw = { (u32)q0 | ((u32)q1 << 16), (u32)q2 | ((u32)q3 << 16) };
            *(uint2*)&xf[r][c4 * 4] = pw;
        }
    }
    __syncthreads();

    // ---- layer 1 (f16 MFMA, prefetched B) + layer 2 (MFMA) ----
    f32x4 acc2 = (f32x4){0.f, 0.f, 0.f, 0.f};   // layer-2 accum (waves 0..3)
    for (int hl = 0; hl < 2; ++hl) {
        f32x4 acc[4][2];
        #pragma unroll
        for (int m = 0; m < 4; ++m) {
            acc[m][0] = (f32x4){0.f,0.f,0.f,0.f};
            acc[m][1] = (f32x4){0.f,0.f,0.f,0.f};
        }
        // wave w owns n = hl*256 + w*32 + i2*16 + ln
        const u16* bb = wt1f + (size_t)(hl * 16 + w * 2) * 4096 + lane * 8;
        f16x8 Bf[16];
        #pragma unroll
        for (int kk = 0; kk < 8; ++kk) {
            Bf[kk]     = *(const f16x8*)(bb + kk * 512);
            Bf[8 + kk] = *(const f16x8*)(bb + 4096 + kk * 512);
        }
        #pragma unroll
        for (int kk = 0; kk < 8; ++kk) {
            #pragma unroll
            for (int m = 0; m < 4; ++m) {
                f16x8 a = *(const f16x8*)(&xf[m * 16 + ln][kk * 32 + quad * 8]);
                acc[m][0] = MF(a, Bf[kk],     acc[m][0]);
                acc[m][1] = MF(a, Bf[8 + kk], acc[m][1]);
            }
        }
        // bias + relu + f16 -> hbuf [64][264]
        #pragma unroll
        for (int m = 0; m < 4; ++m)
            #pragma unroll
            for (int i2 = 0; i2 < 2; ++i2) {
                int nloc = w * 32 + i2 * 16 + ln;
                float bias = bt1[hl * 256 + nloc];
                #pragma unroll
                for (int r = 0; r < 4; ++r) {
                    float hv = acc[m][i2][r] + bias; hv = hv > 0.f ? hv : 0.f;
                    hbuf[(m * 16 + quad * 4 + r) * 264 + nloc] = f16b(hv);
                }
            }
        __syncthreads();
        // layer 2: waves 0..3, wave w = m-frag w, K=256 per half
        if (w < 4) {
            f16x8 wbf[8];
            #pragma unroll
            for (int kk = 0; kk < 8; ++kk)
                wbf[kk] = *(const f16x8*)(wt2f + (hl * 8 + kk) * 512 + lane * 8);
            #pragma unroll
            for (int kk = 0; kk < 8; ++kk) {
                f16x8 ha = *(const f16x8*)(&hbuf[(w * 16 + ln) * 264 + kk * 32 + quad * 8]);
                acc2 = MF(ha, wbf[kk], acc2);
            }
        }
        __syncthreads();   // before next half overwrites hbuf
    }
    if (w < 4 && ln < 10) {
        #pragma unroll
        for (int r = 0; r < 4; ++r)
            lg[w * 16 + quad * 4 + r][ln] = acc2[r] + bt2[ln];
    }
    __syncthreads();

    // ---- margin flag (-> global list) + bitmap + per-patch row lists ----
    if (t < 64) {
        float l[10];
        #pragma unroll
        for (int c = 0; c < 10; ++c) l[c] = lg[t][c];
        float b0 = -1e30f; int i0 = 0;
        #pragma unroll
        for (int c = 0; c < 10; ++c) if (l[c] > b0) { b0 = l[c]; i0 = c; }
        float b1 = -1e30f; int i1 = 0;
        #pragma unroll
        for (int c = 0; c < 10; ++c) { if (c == i0) continue; if (l[c] > b1) { b1 = l[c]; i1 = c; } }
        float b2v = -1e30f;
        #pragma unroll
        for (int c = 0; c < 10; ++c) { if (c == i0 || c == i1) continue; if (l[c] > b2v) b2v = l[c]; }
        if (b0 - b1 < MARGIN || b1 - b2v < MARGIN) {
            u32 idx = atomicAdd(gcnt, 1u);
            glist[idx] = (u32)(row0 + t);
        }
        u32 exact = 0, fb = 0;
        #pragma unroll
        for (int p = 0; p < 10; ++p) {
            int a = rdds[2 * p], bq = rdds[2 * p + 1];
            if (i0 == a && i1 == bq) exact |= 1u << p;
            if (i0 == a)             fb    |= 1u << p;
        }
        u32 bits = exact ? exact : fb;
        while (bits) {
            int p = __ffs(bits) - 1;
            bits &= bits - 1;
            u32 idx = atomicAdd(&pcnt[p], 1u);
            plist[p][idx] = (u32)t;
        }
    }
    __syncthreads();
    if (t < 10) {
        int L = (int)pcnt[t];
        for (int base = 0; base < L; base += 16) {
            u32 e = atomicAdd(&nwork, 1u);
            wq[e] = ((u32)t << 8) | (u32)base;
        }
    }
    __syncthreads();

    // ---- gated patch nets: f16 MFMA, double-buffered B prefetch ----
    {
        const u32 nw = nwork;
        for (u32 ii = w; ii < nw; ii += 8) {
            const u32 item = wq[ii];
            const int p = (int)(item >> 8), mbase = (int)(item & 255);
            const int Lp = (int)pcnt[p];
            const int mi = mbase + ln;
            const int arow = (mi < Lp) ? (int)plist[p][mi] : (int)plist[p][0];
            const u16* xr = &xf[arow][0];
            const u16* wb = wp1f + (size_t)p * 32768 + lane * 8;
            f32x4 pacc[8];
            #pragma unroll
            for (int i2 = 0; i2 < 8; ++i2) pacc[i2] = (f32x4){0.f,0.f,0.f,0.f};
            f16x8 W0[8], W1[8];
            #pragma unroll
            for (int i2 = 0; i2 < 8; ++i2)
                W0[i2] = *(const f16x8*)(wb + (i2 * 8 + 0) * 512);
            #pragma unroll
            for (int kk = 0; kk < 8; kk += 2) {
                #pragma unroll
                for (int i2 = 0; i2 < 8; ++i2)
                    W1[i2] = *(const f16x8*)(wb + (i2 * 8 + kk + 1) * 512);
                f16x8 a0 = *(const f16x8*)(xr + kk * 32 + quad * 8);
                #pragma unroll
                for (int i2 = 0; i2 < 8; ++i2) pacc[i2] = MF(a0, W0[i2], pacc[i2]);
                if (kk + 2 < 8) {
                    #pragma unroll
                    for (int i2 = 0; i2 < 8; ++i2)
                        W0[i2] = *(const f16x8*)(wb + (i2 * 8 + kk + 2) * 512);
                }
                f16x8 a1 = *(const f16x8*)(xr + (kk + 1) * 32 + quad * 8);
                #pragma unroll
                for (int i2 = 0; i2 < 8; ++i2) pacc[i2] = MF(a1, W1[i2], pacc[i2]);
            }
            // hp: [16][136] per-wave scratch (row stride 272B)
            u16* hp = &hbuf[w * 2176];
            #pragma unroll
            for (int i2 = 0; i2 < 8; ++i2) {
                float bias = bp1[p * 128 + i2 * 16 + ln];
                #pragma unroll
                for (int r = 0; r < 4; ++r) {
                    float hv = pacc[i2][r] + bias; hv = hv > 0.f ? hv : 0.f;
                    hp[(quad * 4 + r) * 136 + i2 * 16 + ln] = f16b(hv);
                }
            }
            f32x4 po = (f32x4){0.f,0.f,0.f,0.f};
            f16x8 wpf[4];
            #pragma unroll
            for (int kk = 0; kk < 4; ++kk)
                wpf[kk] = *(const f16x8*)(wp2f + p * 2048 + kk * 512 + lane * 8);
            #pragma unroll
            for (int kk = 0; kk < 4; ++kk) {
                f16x8 ha = *(const f16x8*)(&hp[ln * 136 + kk * 32 + quad * 8]);
                po = MF(ha, wpf[kk], po);
            }
            if (ln < 10) {
                float b2 = bp2[p * 10 + ln];
                #pragma unroll
                for (int r = 0; r < 4; ++r) {
                    int mi2 = mbase + quad * 4 + r;
                    if (mi2 < Lp)
                        atomicAdd(&oacc[plist[p][mi2]][ln], po[r] + b2);
                }
            }
        }
    }
    __syncthreads();

    for (int i = t; i < 640; i += 512)
        out[(size_t)row0 * 10 + i] = ((float*)lg)[i] + ((float*)oacc)[i];
}

// ---------------------------------------------------------------------------
// fix: high-precision recompute for margin-flagged rows, MFMA throughout.
// Split-f16 (hi + 2048*lo) layer1+2 reproduces fp32 logits to ~1e-7 ->
// exact bitmap; patch nets plain f16 MFMA. Prefetched B-fragments.
// ---------------------------------------------------------------------------
__global__ __launch_bounds__(512, 1) void fix_kernel(
    const float* __restrict__ x, const float* __restrict__ bt1,
    const float* __restrict__ bt2,
    const float* __restrict__ bp1, const float* __restrict__ bp2,
    const int* __restrict__ rdd,
    const u16* __restrict__ wt1f, const u16* __restrict__ wt1g,
    const u16* __restrict__ wt2f, const u16* __restrict__ wt2g,
    const u16* __restrict__ wp1f, const u16* __restrict__ wp2f,
    const u32* __restrict__ gcnt, const u32* __restrict__ glist,
    float* __restrict__ out)
{
    __shared__ u16 xfh[64][264];     // 33792 B  x hi
    __shared__ u16 xfl[64][264];     // 33792 B  x scaled-lo
    __shared__ u16 hb2[2][16896];    // 67584 B  h hi/lo halves; [0] reused as hp
    __shared__ float lg[64][10];
    __shared__ float oacc[64][10];
    __shared__ u32 rows[64];
    __shared__ u32 plist[10][64];
    __shared__ u32 pcnt[10];
    __shared__ int rdds[20];
    __shared__ u32 wq[40];
    __shared__ u32 nwork;
    // ~143 KB -> 1 block/CU

    const int t = threadIdx.x;
    const int lane = t & 63;
    const int w = t >> 6;
    const int ln = lane & 15;
    const int quad = lane >> 4;
    const u32 cnt = gcnt[0];
    if (t < 20) rdds[t] = rdd[t];

    for (u32 base = blockIdx.x * 64; base < cnt; base += gridDim.x * 64) {
        __syncthreads();                       // protect buffers from prev iter
        const int R = (int)min(64u, cnt - base);
        if (t < 64) rows[t] = glist[base + (t < R ? t : 0)];
        if (t < 10) pcnt[t] = 0;
        if (t == 0) nwork = 0;
        for (int i = t; i < 640; i += 512) ((float*)oacc)[i] = 0.f;
        __syncthreads();

        // ---- gather flagged x rows -> hi/lo f16 LDS ----
        {
            float4 v[8];
            #pragma unroll
            for (int i = 0; i < 8; ++i) {
                int f = t + 512 * i;
                int r = f >> 6, c4 = f & 63;
                v[i] = *(const float4*)(x + (size_t)rows[r] * 256 + c4 * 4);
            }
            #pragma unroll
            for (int i = 0; i < 8; ++i) {
                int f = t + 512 * i;
                int r = f >> 6, c4 = f & 63;
                f16 h0 = (f16)v[i].x, h1 = (f16)v[i].y, h2 = (f16)v[i].z, h3 = (f16)v[i].w;
                u16 q0 = __builtin_bit_cast(u16, h0), q1 = __builtin_bit_cast(u16, h1);
                u16 q2 = __builtin_bit_cast(u16, h2), q3 = __builtin_bit_cast(u16, h3);
                u16 l0 = f16b(LSC * (v[i].x - (float)h0)), l1 = f16b(LSC * (v[i].y - (float)h1));
                u16 l2 = f16b(LSC * (v[i].z - (float)h2)), l3 = f16b(LSC * (v[i].w - (float)h3));
                uint2 hw = { (u32)q0 | ((u32)q1 << 16), (u32)q2 | ((u32)q3 << 16) };
                uint2 lw = { (u32)l0 | ((u32)l1 << 16), (u32)l2 | ((u32)l3 << 16) };
                *(uint2*)&xfh[r][c4 * 4] = hw;
                *(uint2*)&xfl[r][c4 * 4] = lw;
            }
        }
        __syncthreads();

        // ---- layer 1 split-f16 (3 MFMA) + layer 2 split-f16 (3 MFMA) ----
        f32x4 acc2h = (f32x4){0.f,0.f,0.f,0.f};
        f32x4 acc2s = (f32x4){0.f,0.f,0.f,0.f};
        for (int hl = 0; hl < 2; ++hl) {
            f32x4 accH[4][2], accS[4][2];
            #pragma unroll
            for (int m = 0; m < 4; ++m)
                #pragma unroll
                for (int i2 = 0; i2 < 2; ++i2) {
                    accH[m][i2] = (f32x4){0.f,0.f,0.f,0.f};
                    accS[m][i2] = (f32x4){0.f,0.f,0.f,0.f};
                }
            const size_t boff = (size_t)(hl * 16 + w * 2) * 4096 + lane * 8;
            const u16* bbh = wt1f + boff;
            const u16* bbl = wt1g + boff;
            // two kk-quartet batches, 16 prefetched frags each
            #pragma unroll
            for (int half = 0; half < 2; ++half) {
                f16x8 F[16];
                #pragma unroll
                for (int q = 0; q < 4; ++q) {
                    int kk = half * 4 + q;
                    F[q]      = *(const f16x8*)(bbh + kk * 512);
                    F[4 + q]  = *(const f16x8*)(bbh + 4096 + kk * 512);
                    F[8 + q]  = *(const f16x8*)(bbl + kk * 512);
                    F[12 + q] = *(const f16x8*)(bbl + 4096 + kk * 512);
                }
                #pragma unroll
                for (int q = 0; q < 4; ++q) {
                    int kk = half * 4 + q;
                    #pragma unroll
                    for (int m = 0; m < 4; ++m) {
                        f16x8 ah = *(const f16x8*)(&xfh[m * 16 + ln][kk * 32 + quad * 8]);
                        f16x8 al = *(const f16x8*)(&xfl[m * 16 + ln][kk * 32 + quad * 8]);
                        accH[m][0] = MF(ah, F[q],      accH[m][0]);
                        accS[m][0] = MF(ah, F[8 + q],  accS[m][0]);
                        accS[m][0] = MF(al, F[q],      accS[m][0]);
                        accH[m][1] = MF(ah, F[4 + q],  accH[m][1]);
                        accS[m][1] = MF(ah, F[12 + q], accS[m][1]);
                        accS[m][1] = MF(al, F[4 + q],  accS[m][1]);
                    }
                }
            }
            // bias + relu + hi/lo split -> hb2
            #pragma unroll
            for (int m = 0; m < 4; ++m)
                #pragma unroll
                for (int i2 = 0; i2 < 2; ++i2) {
                    int nloc = w * 32 + i2 * 16 + ln;
                    float bias = bt1[hl * 256 + nloc];
                    #pragma unroll
                    for (int r = 0; r < 4; ++r) {
                        float hv = accH[m][i2][r] + accS[m][i2][r] * LSCI + bias;
                        hv = hv > 0.f ? hv : 0.f;
                        f16 hh = (f16)hv;
                        int idx = (m * 16 + quad * 4 + r) * 264 + nloc;
                        hb2[0][idx] = __builtin_bit_cast(u16, hh);
                        hb2[1][idx] = f16b(LSC * (hv - (float)hh));
                    }
                }
            __syncthreads();
            if (w < 4) {
                f16x8 WH[8], WL[8];
                #pragma unroll
                for (int kk = 0; kk < 8; ++kk) {
                    WH[kk] = *(const f16x8*)(wt2f + (hl * 8 + kk) * 512 + lane * 8);
                    WL[kk] = *(const f16x8*)(wt2g + (hl * 8 + kk) * 512 + lane * 8);
                }
                #pragma unroll
                for (int kk = 0; kk < 8; ++kk) {
                    int hidx = (w * 16 + ln) * 264 + kk * 32 + quad * 8;
                    f16x8 hah = *(const f16x8*)(&hb2[0][hidx]);
                    f16x8 hal = *(const f16x8*)(&hb2[1][hidx]);
                    acc2h = MF(hah, WH[kk], acc2h);
                    acc2s = MF(hah, WL[kk], acc2s);
                    acc2s = MF(hal, WH[kk], acc2s);
                }
            }
            __syncthreads();
        }
        if (w < 4 && ln < 10) {
            #pragma unroll
            for (int r = 0; r < 4; ++r)
                lg[w * 16 + quad * 4 + r][ln] = acc2h[r] + acc2s[r] * LSCI + bt2[ln];
        }
        __syncthreads();

        // ---- exact bitmap + per-patch row lists ----
        if (t < R) {
            float l[10];
            #pragma unroll
            for (int c = 0; c < 10; ++c) l[c] = lg[t][c];
            float b0 = -1e30f; int i0 = 0;
            #pragma unroll
            for (int c = 0; c < 10; ++c) if (l[c] > b0) { b0 = l[c]; i0 = c; }
            float b1 = -1e30f; int i1 = 0;
            #pragma unroll
            for (int c = 0; c < 10; ++c) { if (c == i0) continue; if (l[c] > b1) { b1 = l[c]; i1 = c; } }
            u32 exact = 0, fb = 0;
            #pragma unroll
            for (int p = 0; p < 10; ++p) {
                int a = rdds[2 * p], bq = rdds[2 * p + 1];
                if (i0 == a && i1 == bq) exact |= 1u << p;
                if (i0 == a)             fb    |= 1u << p;
            }
            u32 bits = exact ? exact : fb;
            while (bits) {
                int p = __ffs(bits) - 1;
                bits &= bits - 1;
                u32 idx = atomicAdd(&pcnt[p], 1u);
                plist[p][idx] = (u32)t;
            }
        }
        __syncthreads();
        if (t < 10) {
            int L = (int)pcnt[t];
            for (int b2 = 0; b2 < L; b2 += 16) {
                u32 e = atomicAdd(&nwork, 1u);
                wq[e] = ((u32)t << 8) | (u32)b2;
            }
        }
        __syncthreads();

        // ---- patch nets: plain f16 MFMA, double-buffered B prefetch ----
        {
            const u32 nw = nwork;
            u16* hbuf = &hb2[0][0];
            for (u32 ii = w; ii < nw; ii += 8) {
                const u32 item = wq[ii];
                const int p = (int)(item >> 8), mbase = (int)(item & 255);
                const int Lp = (int)pcnt[p];
                const int mi = mbase + ln;
                const int arow = (mi < Lp) ? (int)plist[p][mi] : (int)plist[p][0];
                const u16* xr = &xfh[arow][0];
                const u16* wb = wp1f + (size_t)p * 32768 + lane * 8;
                f32x4 pacc[8];
                #pragma unroll
                for (int i2 = 0; i2 < 8; ++i2) pacc[i2] = (f32x4){0.f,0.f,0.f,0.f};
                f16x8 W0[8], W1[8];
                #pragma unroll
                for (int i2 = 0; i2 < 8; ++i2)
                    W0[i2] = *(const f16x8*)(wb + (i2 * 8 + 0) * 512);
                #pragma unroll
                for (int kk = 0; kk < 8; kk += 2) {
                    #pragma unroll
                    for (int i2 = 0; i2 < 8; ++i2)
                        W1[i2] = *(const f16x8*)(wb + (i2 * 8 + kk + 1) * 512);
                    f16x8 a0 = *(const f16x8*)(xr + kk * 32 + quad * 8);
                    #pragma unroll
                    for (int i2 = 0; i2 < 8; ++i2) pacc[i2] = MF(a0, W0[i2], pacc[i2]);
                    if (kk + 2 < 8) {
                        #pragma unroll
                        for (int i2 = 0; i2 < 8; ++i2)
                            W0[i2] = *(const f16x8*)(wb + (i2 * 8 + kk + 2) * 512);
                    }
                    f16x8 a1 = *(const f16x8*)(xr + (kk + 1) * 32 + quad * 8);
                    #pragma unroll
                    for (int i2 = 0; i2 < 8; ++i2) pacc[i2] = MF(a1, W1[i2], pacc[i2]);
                }
                u16* hp = &hbuf[w * 2176];
                #pragma unroll
                for (int i2 = 0; i2 < 8; ++i2) {
                    float bias = bp1[p * 128 + i2 * 16 + ln];
                    #pragma unroll
                    for (int r = 0; r < 4; ++r) {
                        float hv = pacc[i2][r] + bias; hv = hv > 0.f ? hv : 0.f;
                        hp[(quad * 4 + r) * 136 + i2 * 16 + ln] = f16b(hv);
                    }
                }
                f32x4 po = (f32x4){0.f,0.f,0.f,0.f};
                f16x8 wpf[4];
                #pragma unroll
                for (int kk = 0; kk < 4; ++kk)
                    wpf[kk] = *(const f16x8*)(wp2f + p * 2048 + kk * 512 + lane * 8);
                #pragma unroll
                for (int kk = 0; kk < 4; ++kk) {
                    f16x8 ha = *(const f16x8*)(&hp[ln * 136 + kk * 32 + quad * 8]);
                    po = MF(ha, wpf[kk], po);
                }
                if (ln < 10) {
                    float b2 = bp2[p * 10 + ln];
                    #pragma unroll
                    for (int r = 0; r < 4; ++r) {
                        int mi2 = mbase + quad * 4 + r;
                        if (mi2 < Lp)
                            atomicAdd(&oacc[plist[p][mi2]][ln], po[r] + b2);
                    }
                }
            }
        }
        __syncthreads();

        for (int i = t; i < R * 10; i += 512) {
            int r = i / 10, c = i % 10;
            out[(size_t)rows[r] * 10 + c] = lg[r][c] + oacc[r][c];
        }
    }
}

extern "C" void kernel_launch(void* const* d_in, const int* in_sizes, int n_in,
                              void* d_out, int out_size, void* d_ws, size_t ws_size,
                              hipStream_t stream) {
    const float* x   = (const float*)d_in[0];
    const float* Wt1 = (const float*)d_in[1];
    const float* bt1 = (const float*)d_in[2];
    const float* Wt2 = (const float*)d_in[3];
    const float* bt2 = (const float*)d_in[4];
    const float* Wp1 = (const float*)d_in[5];
    const float* bp1 = (const float*)d_in[6];
    const float* Wp2 = (const float*)d_in[7];
    const float* bp2 = (const float*)d_in[8];
    const int* rdd = (const int*)d_in[9];
    float* out = (float*)d_out;

    u16* wt1f = (u16*)d_ws;                 // 131072 u16
    u16* wt1g = wt1f + 131072;              // 131072 u16
    u16* wp1f = wt1g + 131072;              // 327680 u16
    u16* wt2f = wp1f + 327680;              // 8192 u16
    u16* wt2g = wt2f + 8192;                // 8192 u16
    u16* wp2f = wt2g + 8192;                // 20480 u16
    u32* gcnt  = (u32*)(wp2f + 20480);      // 1 (+pad to 16)
    u32* glist = gcnt + 16;                 // 65536 u32

    hipLaunchKernelGGL(conv_kernel, dim3(113), dim3(256), 0, stream,
                       Wt1, Wp1, Wt2, Wp2, wt1f, wt1g, wp1f, wt2f, wt2g, wp2f, gcnt);
    hipLaunchKernelGGL(netsum_kernel, dim3(1024), dim3(512), 0, stream,
                       x, bt1, bt2, bp1, bp2, rdd,
                       wt1f, wp1f, wt2f, wp2f, out, gcnt, glist);
    hipLaunchKernelGGL(fix_kernel, dim3(256), dim3(512), 0, stream,
                       x, bt1, bt2, bp1, bp2, rdd,
                       wt1f, wt1g, wt2f, wt2g, wp1f, wp2f,
                       gcnt, glist, out);
}

// Round 5
// 198.539 us; speedup vs baseline: 2.1023x; 1.0471x over previous
//
#include <hip/hip_runtime.h>

typedef unsigned int u32;
typedef unsigned short u16;
typedef _Float16 f16;
typedef __attribute__((ext_vector_type(8))) _Float16 f16x8;
typedef __attribute__((ext_vector_type(4))) float f32x4;

#define MARGIN 1e-2f
#define LSC 2048.0f          // lo-split scale (keeps lo terms normal in f16)
#define LSCI (1.0f/2048.0f)

__device__ __forceinline__ u16 f16b(float f) {
    return __builtin_bit_cast(u16, (f16)f);
}
__device__ __forceinline__ f32x4 MF(f16x8 a, f16x8 b, f32x4 c) {
    return __builtin_amdgcn_mfma_f32_16x16x32_f16(a, b, c, 0, 0, 0);
}
__device__ __forceinline__ uint4 pack8(const u16 v[8]) {
    uint4 pk;
    pk.x = (u32)v[0] | ((u32)v[1] << 16);
    pk.y = (u32)v[2] | ((u32)v[3] << 16);
    pk.z = (u32)v[4] | ((u32)v[5] << 16);
    pk.w = (u32)v[6] | ((u32)v[7] << 16);
    return pk;
}

// ---------------------------------------------------------------------------
// conv: weights -> f16 MFMA-fragment-linear layouts (hi + scaled-lo for the
// exact-fix path). frag(nf,kk) of [K x N]: lane l (ln=l&15, quad=l>>4) holds
// 8 f16 = W[kk*32+quad*8+j][nf*16+ln], at (nf*8+kk)*512 + l*8 (u16 units).
// ---------------------------------------------------------------------------
__global__ __launch_bounds__(256) void conv_kernel(
    const float* __restrict__ Wt1, const float* __restrict__ Wp1,
    const float* __restrict__ Wt2, const float* __restrict__ Wp2,
    u16* __restrict__ wt1f, u16* __restrict__ wt1g, u16* __restrict__ wp1f,
    u16* __restrict__ wt2f, u16* __restrict__ wt2g, u16* __restrict__ wp2f,
    u32* __restrict__ gcnt)
{
    __shared__ float tile[64][68];
    const int t = threadIdx.x;
    const int b = blockIdx.x;

    if (b == 112) {
        if (t == 0) gcnt[0] = 0;
        // wt2f/wt2g: 16 kk-frags of Wt2 [512 x 10->16]
        for (int cc = t; cc < 1024; cc += 256) {
            int kk = cc >> 6, l = cc & 63, ln = l & 15, quad = l >> 4;
            u16 vh[8], vl[8];
            #pragma unroll
            for (int j = 0; j < 8; ++j) {
                int k = kk * 32 + quad * 8 + j;
                float f = (ln < 10) ? Wt2[k * 10 + ln] : 0.f;
                f16 h = (f16)f;
                vh[j] = __builtin_bit_cast(u16, h);
                vl[j] = f16b(LSC * (f - (float)h));
            }
            *(uint4*)(wt2f + kk * 512 + l * 8) = pack8(vh);
            *(uint4*)(wt2g + kk * 512 + l * 8) = pack8(vl);
        }
        // wp2f: per p, 4 kk-frags of Wp2[p] [128 x 10->16] (hi only)
        for (int cc = t; cc < 2560; cc += 256) {
            int p = cc >> 8, rem = cc & 255, kk = rem >> 6, l = rem & 63;
            int ln = l & 15, quad = (l >> 4) & 3;
            u16 v[8];
            #pragma unroll
            for (int j = 0; j < 8; ++j) {
                int k = kk * 32 + quad * 8 + j;
                v[j] = f16b(ln < 10 ? Wp2[p * 1280 + k * 10 + ln] : 0.f);
            }
            *(uint4*)(wp2f + p * 2048 + kk * 512 + l * 8) = pack8(v);
        }
        return;
    }

    const float* src; int src_ld;
    u16 *dsth, *dstl; int nf0, kk0;
    if (b < 32) {
        int kt = b & 3, nt = b >> 2;
        src = Wt1 + (size_t)(kt * 64) * 512 + nt * 64; src_ld = 512;
        dsth = wt1f; dstl = wt1g; nf0 = nt * 4; kk0 = kt * 2;
    } else {
        int j = b - 32, p = j >> 3, r = j & 7;
        int kt = r & 3, nt = r >> 2;
        src = Wp1 + (size_t)p * 32768 + (size_t)(kt * 64) * 128 + nt * 64; src_ld = 128;
        dsth = wp1f + p * 32768; dstl = nullptr; nf0 = nt * 4; kk0 = kt * 2;
    }
    {
        const int kr = t >> 2, c0 = (t & 3) * 16;
        #pragma unroll
        for (int u = 0; u < 4; ++u) {
            float4 v = *(const float4*)(src + (size_t)kr * src_ld + c0 + u * 4);
            tile[kr][c0 + u*4 + 0] = v.x;
            tile[kr][c0 + u*4 + 1] = v.y;
            tile[kr][c0 + u*4 + 2] = v.z;
            tile[kr][c0 + u*4 + 3] = v.w;
        }
    }
    __syncthreads();
    #pragma unroll
    for (int s = 0; s < 2; ++s) {
        int cc = t + 256 * s;              // 512 chunks per 64x64 tile
        int l = cc & 63, fp = cc >> 6, nfl = fp >> 1, kkl = fp & 1;
        int ln = l & 15, quad = (l >> 4) & 3;
        int nloc = nfl * 16 + ln, kloc = kkl * 32 + quad * 8;
        u16 vh[8], vl[8];
        #pragma unroll
        for (int j = 0; j < 8; ++j) {
            float f = tile[kloc + j][nloc];
            f16 h = (f16)f;
            vh[j] = __builtin_bit_cast(u16, h);
            vl[j] = f16b(LSC * (f - (float)h));
        }
        size_t off = (size_t)((nf0 + nfl) * 8 + (kk0 + kkl)) * 512 + l * 8;
        *(uint4*)(dsth + off) = pack8(vh);
        if (dstl) *(uint4*)(dstl + off) = pack8(vl);
    }
}

// ---------------------------------------------------------------------------
// netsum: per 64-row block. Layer-1 in 4 n-quarters: one B-frag per wave per
// kk with a 2-register rotating prefetch (R4's big prefetch arrays spilled to
// scratch: WRITE_SIZE 2.6->34 MB; this keeps in-flight state at ~8 VGPRs).
// ---------------------------------------------------------------------------
__global__ __launch_bounds__(512, 4) void netsum_kernel(
    const float* __restrict__ x, const float* __restrict__ bt1,
    const float* __restrict__ bt2,
    const float* __restrict__ bp1, const float* __restrict__ bp2,
    const int* __restrict__ rdd,
    const u16* __restrict__ wt1f, const u16* __restrict__ wp1f,
    const u16* __restrict__ wt2f, const u16* __restrict__ wp2f,
    float* __restrict__ out, u32* __restrict__ gcnt, u32* __restrict__ glist)
{
    __shared__ u16 xf[64][264];      // 33792 B  (x in f16, row stride 528B)
    __shared__ u16 scratch[17408];   // 34816 B  hq[64][136] (layer1) / hp 8x2176 (patch)
    __shared__ float lg[64][10];
    __shared__ float oacc[64][10];
    __shared__ u32 plist[10][64];
    __shared__ u32 pcnt[10];
    __shared__ int rdds[20];
    __shared__ u32 wq[40];
    __shared__ u32 nwork;
    // total ~76.6 KB -> 2 blocks/CU

    const int t = threadIdx.x;
    const int lane = t & 63;
    const int w = t >> 6;
    const int ln = lane & 15;
    const int quad = lane >> 4;
    const int row0 = blockIdx.x * 64;

    if (t < 10) pcnt[t] = 0;
    if (t < 20) rdds[t] = rdd[t];
    if (t == 0) nwork = 0;
    for (int i = t; i < 640; i += 512) ((float*)oacc)[i] = 0.f;

    // ---- stage x -> f16 LDS (coalesced) ----
    #pragma unroll
    for (int i = 0; i < 8; ++i) {
        int f = t + 512 * i;           // float4 index 0..4095
        int r = f >> 6, c4 = f & 63;
        float4 v = *(const float4*)(x + (size_t)(row0 + r) * 256 + c4 * 4);
        u16 q0 = f16b(v.x), q1 = f16b(v.y), q2 = f16b(v.z), q3 = f16b(v.w);
        uint2 pw = { (u32)q0 | ((u32)q1 << 16), (u32)q2 | ((u32)q3 << 16) };
        *(uint2*)&xf[r][c4 * 4] = pw;
    }
    __syncthreads();

    // ---- layer 1 in 4 n-quarters + layer-2 accumulation (waves 0..3) ----
    f32x4 acc2 = (f32x4){0.f, 0.f, 0.f, 0.f};
    u16* hq = scratch;                       // [64][136]
    for (int q = 0; q < 4; ++q) {
        f32x4 acc[4];
        #pragma unroll
        for (int m = 0; m < 4; ++m) acc[m] = (f32x4){0.f,0.f,0.f,0.f};
        // wave w owns n = q*128 + w*16 + ln  (frag nf = q*8 + w)
        const u16* bb = wt1f + (size_t)((q * 8 + w) * 8) * 512 + (size_t)lane * 8;
        f16x8 wc = *(const f16x8*)bb;              // kk = 0
        #pragma unroll
        for (int kk = 0; kk < 8; ++kk) {
            f16x8 wn = wc;
            if (kk < 7) wn = *(const f16x8*)(bb + (kk + 1) * 512);
            #pragma unroll
            for (int m = 0; m < 4; ++m) {
                f16x8 a = *(const f16x8*)(&xf[m * 16 + ln][kk * 32 + quad * 8]);
                acc[m] = MF(a, wc, acc[m]);
            }
            wc = wn;
        }
        // bias + relu + f16 -> hq [64][136]
        {
            const int nloc = w * 16 + ln;
            const float bias = bt1[q * 128 + nloc];
            #pragma unroll
            for (int m = 0; m < 4; ++m)
                #pragma unroll
                for (int r = 0; r < 4; ++r) {
                    float hv = acc[m][r] + bias; hv = hv > 0.f ? hv : 0.f;
                    hq[(m * 16 + quad * 4 + r) * 136 + nloc] = f16b(hv);
                }
        }
        __syncthreads();
        // layer 2 partial over this quarter's K=128 (waves 0..3, 16 rows each)
        if (w < 4) {
            #pragma unroll
            for (int kk2 = 0; kk2 < 4; ++kk2) {
                f16x8 ha = *(const f16x8*)(&hq[(w * 16 + ln) * 136 + kk2 * 32 + quad * 8]);
                f16x8 wb = *(const f16x8*)(wt2f + (q * 4 + kk2) * 512 + lane * 8);
                acc2 = MF(ha, wb, acc2);
            }
        }
        __syncthreads();   // before next quarter overwrites hq
    }
    if (w < 4 && ln < 10) {
        #pragma unroll
        for (int r = 0; r < 4; ++r)
            lg[w * 16 + quad * 4 + r][ln] = acc2[r] + bt2[ln];
    }
    __syncthreads();

    // ---- margin flag (-> global list) + bitmap + per-patch row lists ----
    if (t < 64) {
        float l[10];
        #pragma unroll
        for (int c = 0; c < 10; ++c) l[c] = lg[t][c];
        float b0 = -1e30f; int i0 = 0;
        #pragma unroll
        for (int c = 0; c < 10; ++c) if (l[c] > b0) { b0 = l[c]; i0 = c; }
        float b1 = -1e30f; int i1 = 0;
        #pragma unroll
        for (int c = 0; c < 10; ++c) { if (c == i0) continue; if (l[c] > b1) { b1 = l[c]; i1 = c; } }
        float b2v = -1e30f;
        #pragma unroll
        for (int c = 0; c < 10; ++c) { if (c == i0 || c == i1) continue; if (l[c] > b2v) b2v = l[c]; }
        if (b0 - b1 < MARGIN || b1 - b2v < MARGIN) {
            u32 idx = atomicAdd(gcnt, 1u);
            glist[idx] = (u32)(row0 + t);
        }
        u32 exact = 0, fb = 0;
        #pragma unroll
        for (int p = 0; p < 10; ++p) {
            int a = rdds[2 * p], bq = rdds[2 * p + 1];
            if (i0 == a && i1 == bq) exact |= 1u << p;
            if (i0 == a)             fb    |= 1u << p;
        }
        u32 bits = exact ? exact : fb;
        while (bits) {
            int p = __ffs(bits) - 1;
            bits &= bits - 1;
            u32 idx = atomicAdd(&pcnt[p], 1u);
            plist[p][idx] = (u32)t;
        }
    }
    __syncthreads();
    if (t < 10) {
        int L = (int)pcnt[t];
        for (int base = 0; base < L; base += 16) {
            u32 e = atomicAdd(&nwork, 1u);
            wq[e] = ((u32)t << 8) | (u32)base;
        }
    }
    __syncthreads();

    // ---- gated patch nets: n in 2 groups of 4 frags, rotating prefetch ----
    {
        const u32 nw = nwork;
        for (u32 ii = w; ii < nw; ii += 8) {
            const u32 item = wq[ii];
            const int p = (int)(item >> 8), mbase = (int)(item & 255);
            const int Lp = (int)pcnt[p];
            const int mi = mbase + ln;
            const int arow = (mi < Lp) ? (int)plist[p][mi] : (int)plist[p][0];
            const u16* xr = &xf[arow][0];
            const u16* wb = wp1f + (size_t)p * 32768 + (size_t)lane * 8;
            u16* hp = &scratch[w * 2176];            // [16][136]
            #pragma unroll
            for (int g = 0; g < 2; ++g) {
                f32x4 acc4[4];
                #pragma unroll
                for (int i2 = 0; i2 < 4; ++i2) acc4[i2] = (f32x4){0.f,0.f,0.f,0.f};
                f16x8 wc4[4];
                #pragma unroll
                for (int i2 = 0; i2 < 4; ++i2)
                    wc4[i2] = *(const f16x8*)(wb + ((g * 4 + i2) * 8 + 0) * 512);
                #pragma unroll
                for (int kk = 0; kk < 8; ++kk) {
                    f16x8 wn4[4];
                    #pragma unroll
                    for (int i2 = 0; i2 < 4; ++i2) {
                        wn4[i2] = wc4[i2];
                        if (kk < 7)
                            wn4[i2] = *(const f16x8*)(wb + ((g * 4 + i2) * 8 + kk + 1) * 512);
                    }
                    f16x8 a = *(const f16x8*)(xr + kk * 32 + quad * 8);
                    #pragma unroll
                    for (int i2 = 0; i2 < 4; ++i2) acc4[i2] = MF(a, wc4[i2], acc4[i2]);
                    #pragma unroll
                    for (int i2 = 0; i2 < 4; ++i2) wc4[i2] = wn4[i2];
                }
                #pragma unroll
                for (int i2 = 0; i2 < 4; ++i2) {
                    const int i2g = g * 4 + i2;
                    float bias = bp1[p * 128 + i2g * 16 + ln];
                    #pragma unroll
                    for (int r = 0; r < 4; ++r) {
                        float hv = acc4[i2][r] + bias; hv = hv > 0.f ? hv : 0.f;
                        hp[(quad * 4 + r) * 136 + i2g * 16 + ln] = f16b(hv);
                    }
                }
            }
            f32x4 po = (f32x4){0.f,0.f,0.f,0.f};
            #pragma unroll
            for (int kk = 0; kk < 4; ++kk) {
                f16x8 ha = *(const f16x8*)(&hp[ln * 136 + kk * 32 + quad * 8]);
                f16x8 wb2 = *(const f16x8*)(wp2f + p * 2048 + kk * 512 + lane * 8);
                po = MF(ha, wb2, po);
            }
            if (ln < 10) {
                float b2 = bp2[p * 10 + ln];
                #pragma unroll
                for (int r = 0; r < 4; ++r) {
                    int mi2 = mbase + quad * 4 + r;
                    if (mi2 < Lp)
                        atomicAdd(&oacc[plist[p][mi2]][ln], po[r] + b2);
                }
            }
        }
    }
    __syncthreads();

    for (int i = t; i < 640; i += 512)
        out[(size_t)row0 * 10 + i] = ((float*)lg)[i] + ((float*)oacc)[i];
}

// ---------------------------------------------------------------------------
// fix: high-precision recompute for margin-flagged rows, MFMA throughout.
// Split-f16 (hi + 2048*lo) layer1+2 reproduces fp32 logits to ~1e-7 ->
// exact bitmap; patch nets plain f16 MFMA (rotating prefetch, no big arrays).
// ---------------------------------------------------------------------------
__global__ __launch_bounds__(512, 1) void fix_kernel(
    const float* __restrict__ x, const float* __restrict__ bt1,
    const float* __restrict__ bt2,
    const float* __restrict__ bp1, const float* __restrict__ bp2,
    const int* __restrict__ rdd,
    const u16* __restrict__ wt1f, const u16* __restrict__ wt1g,
    const u16* __restrict__ wt2f, const u16* __restrict__ wt2g,
    const u16* __restrict__ wp1f, const u16* __restrict__ wp2f,
    const u32* __restrict__ gcnt, const u32* __restrict__ glist,
    float* __restrict__ out)
{
    __shared__ u16 xfh[64][264];     // 33792 B  x hi
    __shared__ u16 xfl[64][264];     // 33792 B  x scaled-lo
    __shared__ u16 hb2[2][16896];    // 67584 B  h hi/lo halves; [0] reused as hp
    __shared__ float lg[64][10];
    __shared__ float oacc[64][10];
    __shared__ u32 rows[64];
    __shared__ u32 plist[10][64];
    __shared__ u32 pcnt[10];
    __shared__ int rdds[20];
    __shared__ u32 wq[40];
    __shared__ u32 nwork;
    // ~143 KB -> 1 block/CU

    const int t = threadIdx.x;
    const int lane = t & 63;
    const int w = t >> 6;
    const int ln = lane & 15;
    const int quad = lane >> 4;
    const u32 cnt = gcnt[0];
    if (t < 20) rdds[t] = rdd[t];

    for (u32 base = blockIdx.x * 64; base < cnt; base += gridDim.x * 64) {
        __syncthreads();                       // protect buffers from prev iter
        const int R = (int)min(64u, cnt - base);
        if (t < 64) rows[t] = glist[base + (t < R ? t : 0)];
        if (t < 10) pcnt[t] = 0;
        if (t == 0) nwork = 0;
        for (int i = t; i < 640; i += 512) ((float*)oacc)[i] = 0.f;
        __syncthreads();

        // ---- gather flagged x rows -> hi/lo f16 LDS ----
        #pragma unroll
        for (int i = 0; i < 8; ++i) {
            int f = t + 512 * i;
            int r = f >> 6, c4 = f & 63;
            float4 v = *(const float4*)(x + (size_t)rows[r] * 256 + c4 * 4);
            f16 h0 = (f16)v.x, h1 = (f16)v.y, h2 = (f16)v.z, h3 = (f16)v.w;
            u16 q0 = __builtin_bit_cast(u16, h0), q1 = __builtin_bit_cast(u16, h1);
            u16 q2 = __builtin_bit_cast(u16, h2), q3 = __builtin_bit_cast(u16, h3);
            u16 l0 = f16b(LSC * (v.x - (float)h0)), l1 = f16b(LSC * (v.y - (float)h1));
            u16 l2 = f16b(LSC * (v.z - (float)h2)), l3 = f16b(LSC * (v.w - (float)h3));
            uint2 hw = { (u32)q0 | ((u32)q1 << 16), (u32)q2 | ((u32)q3 << 16) };
            uint2 lw = { (u32)l0 | ((u32)l1 << 16), (u32)l2 | ((u32)l3 << 16) };
            *(uint2*)&xfh[r][c4 * 4] = hw;
            *(uint2*)&xfl[r][c4 * 4] = lw;
        }
        __syncthreads();

        // ---- layer 1 split-f16 (3 MFMA) + layer 2 split-f16 (3 MFMA) ----
        f32x4 acc2h = (f32x4){0.f,0.f,0.f,0.f};
        f32x4 acc2s = (f32x4){0.f,0.f,0.f,0.f};
        for (int hl = 0; hl < 2; ++hl) {
            f32x4 accH[4][2], accS[4][2];
            #pragma unroll
            for (int m = 0; m < 4; ++m)
                #pragma unroll
                for (int i2 = 0; i2 < 2; ++i2) {
                    accH[m][i2] = (f32x4){0.f,0.f,0.f,0.f};
                    accS[m][i2] = (f32x4){0.f,0.f,0.f,0.f};
                }
            const size_t boff = (size_t)(hl * 16 + w * 2) * 4096 + (size_t)lane * 8;
            const u16* bbh = wt1f + boff;
            const u16* bbl = wt1g + boff;
            #pragma unroll
            for (int kk = 0; kk < 8; ++kk) {
                f16x8 bh0 = *(const f16x8*)(bbh + kk * 512);
                f16x8 bh1 = *(const f16x8*)(bbh + 4096 + kk * 512);
                f16x8 bl0 = *(const f16x8*)(bbl + kk * 512);
                f16x8 bl1 = *(const f16x8*)(bbl + 4096 + kk * 512);
                #pragma unroll
                for (int m = 0; m < 4; ++m) {
                    f16x8 ah = *(const f16x8*)(&xfh[m * 16 + ln][kk * 32 + quad * 8]);
                    f16x8 al = *(const f16x8*)(&xfl[m * 16 + ln][kk * 32 + quad * 8]);
                    accH[m][0] = MF(ah, bh0, accH[m][0]);
                    accS[m][0] = MF(ah, bl0, accS[m][0]);
                    accS[m][0] = MF(al, bh0, accS[m][0]);
                    accH[m][1] = MF(ah, bh1, accH[m][1]);
                    accS[m][1] = MF(ah, bl1, accS[m][1]);
                    accS[m][1] = MF(al, bh1, accS[m][1]);
                }
            }
            // bias + relu + hi/lo split -> hb2
            #pragma unroll
            for (int m = 0; m < 4; ++m)
                #pragma unroll
                for (int i2 = 0; i2 < 2; ++i2) {
                    int nloc = w * 32 + i2 * 16 + ln;
                    float bias = bt1[hl * 256 + nloc];
                    #pragma unroll
                    for (int r = 0; r < 4; ++r) {
                        float hv = accH[m][i2][r] + accS[m][i2][r] * LSCI + bias;
                        hv = hv > 0.f ? hv : 0.f;
                        f16 hh = (f16)hv;
                        int idx = (m * 16 + quad * 4 + r) * 264 + nloc;
                        hb2[0][idx] = __builtin_bit_cast(u16, hh);
                        hb2[1][idx] = f16b(LSC * (hv - (float)hh));
                    }
                }
            __syncthreads();
            if (w < 4) {
                #pragma unroll
                for (int kk = 0; kk < 8; ++kk) {
                    int hidx = (w * 16 + ln) * 264 + kk * 32 + quad * 8;
                    f16x8 hah = *(const f16x8*)(&hb2[0][hidx]);
                    f16x8 hal = *(const f16x8*)(&hb2[1][hidx]);
                    f16x8 wbh = *(const f16x8*)(wt2f + (hl * 8 + kk) * 512 + lane * 8);
                    f16x8 wbl = *(const f16x8*)(wt2g + (hl * 8 + kk) * 512 + lane * 8);
                    acc2h = MF(hah, wbh, acc2h);
                    acc2s = MF(hah, wbl, acc2s);
                    acc2s = MF(hal, wbh, acc2s);
                }
            }
            __syncthreads();
        }
        if (w < 4 && ln < 10) {
            #pragma unroll
            for (int r = 0; r < 4; ++r)
                lg[w * 16 + quad * 4 + r][ln] = acc2h[r] + acc2s[r] * LSCI + bt2[ln];
        }
        __syncthreads();

        // ---- exact bitmap + per-patch row lists ----
        if (t < R) {
            float l[10];
            #pragma unroll
            for (int c = 0; c < 10; ++c) l[c] = lg[t][c];
            float b0 = -1e30f; int i0 = 0;
            #pragma unroll
            for (int c = 0; c < 10; ++c) if (l[c] > b0) { b0 = l[c]; i0 = c; }
            float b1 = -1e30f; int i1 = 0;
            #pragma unroll
            for (int c = 0; c < 10; ++c) { if (c == i0) continue; if (l[c] > b1) { b1 = l[c]; i1 = c; } }
            u32 exact = 0, fb = 0;
            #pragma unroll
            for (int p = 0; p < 10; ++p) {
                int a = rdds[2 * p], bq = rdds[2 * p + 1];
                if (i0 == a && i1 == bq) exact |= 1u << p;
                if (i0 == a)             fb    |= 1u << p;
            }
            u32 bits = exact ? exact : fb;
            while (bits) {
                int p = __ffs(bits) - 1;
                bits &= bits - 1;
                u32 idx = atomicAdd(&pcnt[p], 1u);
                plist[p][idx] = (u32)t;
            }
        }
        __syncthreads();
        if (t < 10) {
            int L = (int)pcnt[t];
            for (int b2 = 0; b2 < L; b2 += 16) {
                u32 e = atomicAdd(&nwork, 1u);
                wq[e] = ((u32)t << 8) | (u32)b2;
            }
        }
        __syncthreads();

        // ---- patch nets: plain f16 MFMA, rotating 4-frag prefetch ----
        {
            const u32 nw = nwork;
            u16* hbuf = &hb2[0][0];
            for (u32 ii = w; ii < nw; ii += 8) {
                const u32 item = wq[ii];
                const int p = (int)(item >> 8), mbase = (int)(item & 255);
                const int Lp = (int)pcnt[p];
                const int mi = mbase + ln;
                const int arow = (mi < Lp) ? (int)plist[p][mi] : (int)plist[p][0];
                const u16* xr = &xfh[arow][0];
                const u16* wb = wp1f + (size_t)p * 32768 + (size_t)lane * 8;
                u16* hp = &hbuf[w * 2176];
                #pragma unroll
                for (int g = 0; g < 2; ++g) {
                    f32x4 acc4[4];
                    #pragma unroll
                    for (int i2 = 0; i2 < 4; ++i2) acc4[i2] = (f32x4){0.f,0.f,0.f,0.f};
                    f16x8 wc4[4];
                    #pragma unroll
                    for (int i2 = 0; i2 < 4; ++i2)
                        wc4[i2] = *(const f16x8*)(wb + ((g * 4 + i2) * 8 + 0) * 512);
                    #pragma unroll
                    for (int kk = 0; kk < 8; ++kk) {
                        f16x8 wn4[4];
                        #pragma unroll
                        for (int i2 = 0; i2 < 4; ++i2) {
                            wn4[i2] = wc4[i2];
                            if (kk < 7)
                                wn4[i2] = *(const f16x8*)(wb + ((g * 4 + i2) * 8 + kk + 1) * 512);
                        }
                        f16x8 a = *(const f16x8*)(xr + kk * 32 + quad * 8);
                        #pragma unroll
                        for (int i2 = 0; i2 < 4; ++i2) acc4[i2] = MF(a, wc4[i2], acc4[i2]);
                        #pragma unroll
                        for (int i2 = 0; i2 < 4; ++i2) wc4[i2] = wn4[i2];
                    }
                    #pragma unroll
                    for (int i2 = 0; i2 < 4; ++i2) {
                        const int i2g = g * 4 + i2;
                        float bias = bp1[p * 128 + i2g * 16 + ln];
                        #pragma unroll
                        for (int r = 0; r < 4; ++r) {
                            float hv = acc4[i2][r] + bias; hv = hv > 0.f ? hv : 0.f;
                            hp[(quad * 4 + r) * 136 + i2g * 16 + ln] = f16b(hv);
                        }
                    }
                }
                f32x4 po = (f32x4){0.f,0.f,0.f,0.f};
                #pragma unroll
                for (int kk = 0; kk < 4; ++kk) {
                    f16x8 ha = *(const f16x8*)(&hp[ln * 136 + kk * 32 + quad * 8]);
                    f16x8 wb2 = *(const f16x8*)(wp2f + p * 2048 + kk * 512 + lane * 8);
                    po = MF(ha, wb2, po);
                }
                if (ln < 10) {
                    float b2 = bp2[p * 10 + ln];
                    #pragma unroll
                    for (int r = 0; r < 4; ++r) {
                        int mi2 = mbase + quad * 4 + r;
                        if (mi2 < Lp)
                            atomicAdd(&oacc[plist[p][mi2]][ln], po[r] + b2);
                    }
                }
            }
        }
        __syncthreads();

        for (int i = t; i < R * 10; i += 512) {
            int r = i / 10, c = i % 10;
            out[(size_t)rows[r] * 10 + c] = lg[r][c] + oacc[r][c];
        }
    }
}

extern "C" void kernel_launch(void* const* d_in, const int* in_sizes, int n_in,
                              void* d_out, int out_size, void* d_ws, size_t ws_size,
                              hipStream_t stream) {
    const float* x   = (const float*)d_in[0];
    const float* Wt1 = (const float*)d_in[1];
    const float* bt1 = (const float*)d_in[2];
    const float* Wt2 = (const float*)d_in[3];
    const float* bt2 = (const float*)d_in[4];
    const float* Wp1 = (const float*)d_in[5];
    const float* bp1 = (const float*)d_in[6];
    const float* Wp2 = (const float*)d_in[7];
    const float* bp2 = (const float*)d_in[8];
    const int* rdd = (const int*)d_in[9];
    float* out = (float*)d_out;

    u16* wt1f = (u16*)d_ws;                 // 131072 u16
    u16* wt1g = wt1f + 131072;              // 131072 u16
    u16* wp1f = wt1g + 131072;              // 327680 u16
    u16* wt2f = wp1f + 327680;              // 8192 u16
    u16* wt2g = wt2f + 8192;                // 8192 u16
    u16* wp2f = wt2g + 8192;                // 20480 u16
    u32* gcnt  = (u32*)(wp2f + 20480);      // 1 (+pad to 16)
    u32* glist = gcnt + 16;                 // 65536 u32

    hipLaunchKernelGGL(conv_kernel, dim3(113), dim3(256), 0, stream,
                       Wt1, Wp1, Wt2, Wp2, wt1f, wt1g, wp1f, wt2f, wt2g, wp2f, gcnt);
    hipLaunchKernelGGL(netsum_kernel, dim3(1024), dim3(512), 0, stream,
                       x, bt1, bt2, bp1, bp2, rdd,
                       wt1f, wp1f, wt2f, wp2f, out, gcnt, glist);
    hipLaunchKernelGGL(fix_kernel, dim3(256), dim3(512), 0, stream,
                       x, bt1, bt2, bp1, bp2, rdd,
                       wt1f, wt1g, wt2f, wt2g, wp1f, wp2f,
                       gcnt, glist, out);
}